// Round 1
// baseline (17230.244 us; speedup 1.0000x reference)
//
#include <hip/hip_runtime.h>
#include <hip/hip_bf16.h>

#define Bn   4096
#define Jn   17
#define Cn   512
#define Kn   3
#define TOKn 256
#define CHn  2048
#define EPSf 1e-5f

typedef unsigned short u16;

__device__ __forceinline__ float gelu_exact(float x) {
    return 0.5f * x * (1.0f + erff(x * 0.70710678118654752440f));
}
__device__ __forceinline__ float bf2f(u16 u) {
    union { float f; unsigned int i; } w; w.i = ((unsigned int)u) << 16; return w.f;
}
__device__ __forceinline__ u16 f2bf(float f) {
    union { float f; unsigned int i; } w; w.f = f;
    unsigned int x = w.i;
    return (u16)((x + 0x7fffu + ((x >> 16) & 1u)) >> 16);
}
__device__ __forceinline__ void unpack2(unsigned u, float& a, float& b) {
    union { float f; unsigned int i; } t;
    t.i = u << 16;          a = t.f;
    t.i = u & 0xffff0000u;  b = t.f;
}

// ---------------------------------------------------------------- prep: W21->W21T bf16 [Cn][CHn], W22->W22T bf16 [CHn][Cn]
__global__ __launch_bounds__(256) void prep_wT(const float* __restrict__ W21, const float* __restrict__ W22,
                                               u16* __restrict__ W21T, u16* __restrict__ W22T) {
    __shared__ u16 tile[64][65];
    int bid = blockIdx.x;
    const float* src; u16* dst; int srcCols, dstCols, tr, tc;
    if (bid < 256) { src = W21; dst = W21T; srcCols = Cn;  dstCols = CHn; tr = (bid >> 3) * 64; tc = (bid & 7) * 64; }
    else { bid -= 256; src = W22; dst = W22T; srcCols = CHn; dstCols = Cn; tr = (bid >> 5) * 64; tc = (bid & 31) * 64; }
    for (int i = 0; i < 16; ++i) {
        int idx = i * 256 + threadIdx.x;
        int r = idx >> 6, c = idx & 63;
        tile[r][c] = f2bf(src[(size_t)(tr + r) * srcCols + tc + c]);
    }
    __syncthreads();
    for (int i = 0; i < 16; ++i) {
        int idx = i * 256 + threadIdx.x;
        int r = idx >> 6, c = idx & 63;
        dst[(size_t)(tc + r) * dstCols + tr + c] = tile[c][r];
    }
}

// ---------------------------------------------------------------- LN1 stats over J per (b,c)
__global__ __launch_bounds__(256) void ln1_stats(const float* __restrict__ x,
                                                 float* __restrict__ m1, float* __restrict__ r1) {
    int i = blockIdx.x * 256 + threadIdx.x;     // b*Cn + c
    int b = i >> 9, c = i & 511;
    const float* p = x + (size_t)b * (Jn * Cn) + c;
    float s = 0.f, q = 0.f;
    #pragma unroll
    for (int j = 0; j < Jn; ++j) { float v = p[j * Cn]; s += v; q += v * v; }
    float mean = s * (1.0f / Jn);
    float var = q * (1.0f / Jn) - mean * mean;
    var = fmaxf(var, 0.f);
    m1[i] = mean; r1[i] = rsqrtf(var + EPSf);
}

// ---------------------------------------------------------------- MLP1 (token mix): out[b,j,c] = x[b,j,c] + mlp(xn1 row)
__global__ __launch_bounds__(256) void mlp1_kernel(
    const float* __restrict__ x, const float* __restrict__ mean1, const float* __restrict__ rstd1,
    const float* __restrict__ g1, const float* __restrict__ be1,
    const float* __restrict__ W11, const float* __restrict__ b11,
    const float* __restrict__ W12, const float* __restrict__ b12,
    float* __restrict__ out)
{
    __shared__ float sW11[TOKn][20];
    __shared__ float sW12T[TOKn][20];
    __shared__ float sb11[TOKn];
    int tid = threadIdx.x;
    for (int idx = tid; idx < TOKn * Jn; idx += 256) {
        int t = idx / Jn, j = idx - t * Jn;
        sW11[t][j] = W11[idx];
    }
    for (int idx = tid; idx < Jn * TOKn; idx += 256) {
        int j = idx >> 8, t = idx & 255;
        sW12T[t][j] = W12[idx];
    }
    if (tid < TOKn) sb11[tid] = b11[tid];
    __syncthreads();

    int rowb = blockIdx.x * 1024 + (tid << 2);   // b*512 + c0 (4 rows per thread)
    int b = rowb >> 9;
    int c0v = rowb & 511;
    const float* px = x + (size_t)b * (Jn * Cn) + c0v;
    float4 mv = *(const float4*)(mean1 + rowb);
    float4 rv = *(const float4*)(rstd1 + rowb);
    float xn[4][Jn];
    #pragma unroll
    for (int j = 0; j < Jn; ++j) {
        float4 xv = *(const float4*)(px + j * Cn);
        float gj = g1[j], bj = be1[j];
        xn[0][j] = (xv.x - mv.x) * rv.x * gj + bj;
        xn[1][j] = (xv.y - mv.y) * rv.y * gj + bj;
        xn[2][j] = (xv.z - mv.z) * rv.z * gj + bj;
        xn[3][j] = (xv.w - mv.w) * rv.w * gj + bj;
    }
    float acc[4][Jn];
    #pragma unroll
    for (int i = 0; i < 4; ++i)
        #pragma unroll
        for (int j = 0; j < Jn; ++j) acc[i][j] = 0.f;

    for (int t = 0; t < TOKn; ++t) {
        float4 wa = *(const float4*)&sW11[t][0];
        float4 wb = *(const float4*)&sW11[t][4];
        float4 wc = *(const float4*)&sW11[t][8];
        float4 wd = *(const float4*)&sW11[t][12];
        float we = sW11[t][16];
        float bt = sb11[t];
        float h[4];
        #pragma unroll
        for (int i = 0; i < 4; ++i) {
            float pre = bt
              + xn[i][0]*wa.x + xn[i][1]*wa.y + xn[i][2]*wa.z + xn[i][3]*wa.w
              + xn[i][4]*wb.x + xn[i][5]*wb.y + xn[i][6]*wb.z + xn[i][7]*wb.w
              + xn[i][8]*wc.x + xn[i][9]*wc.y + xn[i][10]*wc.z + xn[i][11]*wc.w
              + xn[i][12]*wd.x + xn[i][13]*wd.y + xn[i][14]*wd.z + xn[i][15]*wd.w
              + xn[i][16]*we;
            h[i] = gelu_exact(pre);
        }
        float4 va = *(const float4*)&sW12T[t][0];
        float4 vb = *(const float4*)&sW12T[t][4];
        float4 vc = *(const float4*)&sW12T[t][8];
        float4 vd = *(const float4*)&sW12T[t][12];
        float ve = sW12T[t][16];
        #pragma unroll
        for (int i = 0; i < 4; ++i) {
            acc[i][0]  += h[i]*va.x; acc[i][1]  += h[i]*va.y; acc[i][2]  += h[i]*va.z; acc[i][3]  += h[i]*va.w;
            acc[i][4]  += h[i]*vb.x; acc[i][5]  += h[i]*vb.y; acc[i][6]  += h[i]*vb.z; acc[i][7]  += h[i]*vb.w;
            acc[i][8]  += h[i]*vc.x; acc[i][9]  += h[i]*vc.y; acc[i][10] += h[i]*vc.z; acc[i][11] += h[i]*vc.w;
            acc[i][12] += h[i]*vd.x; acc[i][13] += h[i]*vd.y; acc[i][14] += h[i]*vd.z; acc[i][15] += h[i]*vd.w;
            acc[i][16] += h[i]*ve;
        }
    }
    #pragma unroll
    for (int j = 0; j < Jn; ++j) {
        float4 xv = *(const float4*)(px + j * Cn);
        float bj = b12[j];
        float4 o;
        o.x = xv.x + acc[0][j] + bj;
        o.y = xv.y + acc[1][j] + bj;
        o.z = xv.z + acc[2][j] + bj;
        o.w = xv.w + acc[3][j] + bj;
        *(float4*)(out + (size_t)b * (Jn * Cn) + (size_t)j * Cn + c0v) = o;
    }
}

// ---------------------------------------------------------------- GCN (both stages): out[b,w,o] += sum_{k,c} Wg[k,o,c]*(sum_v xn[b,c,v]*adj[k,v,w]) + bias
// tiles: M(o)=128, b-tile=8 (N=136 cols), K-step 32 over kc=k*512+c
template<int STAGE>
__global__ __launch_bounds__(256) void gcn_kernel(
    const float* __restrict__ xf,          // stage1: x (B,J,C) fp32
    const u16* __restrict__ xh,            // stage2: xn2 (B,J,C) bf16
    const float* __restrict__ mean1, const float* __restrict__ rstd1,
    const float* __restrict__ g1, const float* __restrict__ be1,
    const float* __restrict__ Wg, const float* __restrict__ bg,
    const float* __restrict__ adj,
    float* __restrict__ out)
{
    __shared__ float As[32][132];          // [cl][ol]
    __shared__ float Bs[32][164];          // [cl][bl*20 + w]
    __shared__ float slab[8][32][20];      // [bl][cl][v]
    __shared__ float adjT[Kn][Jn][20];     // [k][w][v]
    __shared__ float adjcs[Kn][Jn];
    __shared__ float gsh[Jn], bsh[Jn];

    int tid = threadIdx.x;
    int o0 = (blockIdx.x & 3) << 7;
    int b0 = (blockIdx.x >> 2) << 3;

    for (int idx = tid; idx < Kn * Jn * Jn; idx += 256) {
        int k = idx / (Jn * Jn); int rem = idx - k * (Jn * Jn);
        int v = rem / Jn; int w = rem - v * Jn;
        adjT[k][w][v] = adj[idx];
    }
    if (STAGE == 1 && tid < Jn) { gsh[tid] = g1[tid]; bsh[tid] = be1[tid]; }
    __syncthreads();
    if (tid < Kn * Jn) {
        int k = tid / Jn, w = tid - k * Jn;
        float s = 0.f;
        #pragma unroll
        for (int v = 0; v < Jn; ++v) s += adjT[k][w][v];
        adjcs[k][w] = s;
    }

    int ot = tid & 31;      // o = o0 + ot*4 + i
    int ct = tid >> 5;      // b = b0 + ct
    float acc[4][Jn];
    #pragma unroll
    for (int i = 0; i < 4; ++i)
        #pragma unroll
        for (int w = 0; w < Jn; ++w) acc[i][w] = 0.f;

    for (int ks = 0; ks < 48; ++ks) {
        int kk = ks >> 4;
        int c0 = (ks & 15) << 5;
        __syncthreads();
        // A tile: Wg[kk][o0+ol][c0+cl]
        {
            const float* wp = Wg + ((size_t)kk * Cn + o0) * Cn + c0;
            #pragma unroll
            for (int i = 0; i < 4; ++i) {
                int f4 = i * 256 + tid;            // 1024 float4
                int ol = f4 >> 3, cq = (f4 & 7) << 2;
                float4 v = *(const float4*)(wp + ol * Cn + cq);
                As[cq + 0][ol] = v.x; As[cq + 1][ol] = v.y; As[cq + 2][ol] = v.z; As[cq + 3][ol] = v.w;
            }
        }
        // slab: xn[b0+bl][c0+cl][v]  (136 rows (bl,v) x 32 cl)
        for (int i = 0; i < 17; ++i) {
            int idx = i * 256 + tid;               // 0..4351
            int rr = idx >> 5, cl = idx & 31;
            int bl = rr / Jn, v = rr - bl * Jn;
            int b = b0 + bl;
            float val;
            if (STAGE == 1) {
                float xv = xf[((size_t)b * Jn + v) * Cn + c0 + cl];
                int sc = b * Cn + c0 + cl;
                val = (xv - mean1[sc]) * rstd1[sc] * gsh[v] + bsh[v];
            } else {
                val = bf2f(xh[((size_t)b * Jn + v) * Cn + c0 + cl]);
            }
            slab[bl][cl][v] = val;
        }
        __syncthreads();
        // build B: Bs[cl][bl*20+w] = sum_v slab[bl][cl][v] * adj[kk][v][w]
        for (int i = 0; i < 17; ++i) {
            int idx = i * 256 + tid;
            int col = idx >> 5, cl = idx & 31;
            int bl = col / Jn, w = col - bl * Jn;
            const float* sp = &slab[bl][cl][0];
            const float* ap = &adjT[kk][w][0];
            float4 s0 = *(const float4*)(sp);      float4 a0 = *(const float4*)(ap);
            float4 s1 = *(const float4*)(sp + 4);  float4 a1 = *(const float4*)(ap + 4);
            float4 s2 = *(const float4*)(sp + 8);  float4 a2 = *(const float4*)(ap + 8);
            float4 s3 = *(const float4*)(sp + 12); float4 a3 = *(const float4*)(ap + 12);
            float r = sp[16] * ap[16];
            r += s0.x*a0.x + s0.y*a0.y + s0.z*a0.z + s0.w*a0.w;
            r += s1.x*a1.x + s1.y*a1.y + s1.z*a1.z + s1.w*a1.w;
            r += s2.x*a2.x + s2.y*a2.y + s2.z*a2.z + s2.w*a2.w;
            r += s3.x*a3.x + s3.y*a3.y + s3.z*a3.z + s3.w*a3.w;
            Bs[cl][bl * 20 + w] = r;
        }
        __syncthreads();
        // main: acc[i][w] += A[o][kc] * B[kc][col]
        #pragma unroll 2
        for (int cl = 0; cl < 32; ++cl) {
            float4 a = *(const float4*)&As[cl][ot << 2];
            const float* bp = &Bs[cl][ct * 20];
            #pragma unroll
            for (int w = 0; w < 16; w += 4) {
                float4 q = *(const float4*)(bp + w);
                acc[0][w+0] += a.x*q.x; acc[0][w+1] += a.x*q.y; acc[0][w+2] += a.x*q.z; acc[0][w+3] += a.x*q.w;
                acc[1][w+0] += a.y*q.x; acc[1][w+1] += a.y*q.y; acc[1][w+2] += a.y*q.z; acc[1][w+3] += a.y*q.w;
                acc[2][w+0] += a.z*q.x; acc[2][w+1] += a.z*q.y; acc[2][w+2] += a.z*q.z; acc[2][w+3] += a.z*q.w;
                acc[3][w+0] += a.w*q.x; acc[3][w+1] += a.w*q.y; acc[3][w+2] += a.w*q.z; acc[3][w+3] += a.w*q.w;
            }
            float q16 = bp[16];
            acc[0][16] += a.x*q16; acc[1][16] += a.y*q16; acc[2][16] += a.z*q16; acc[3][16] += a.w*q16;
        }
    }
    // epilogue: out[b][w][o] += acc + bias(o,w),  bias = sum_k bg[k,o]*colsum_v adj[k,v,w]
    {
        int b = b0 + ct;
        int obase = o0 + (ot << 2);
        float bgv[Kn][4];
        #pragma unroll
        for (int k = 0; k < Kn; ++k)
            #pragma unroll
            for (int i = 0; i < 4; ++i) bgv[k][i] = bg[k * Cn + obase + i];
        #pragma unroll
        for (int w = 0; w < Jn; ++w) {
            float a0 = adjcs[0][w], a1 = adjcs[1][w], a2 = adjcs[2][w];
            float* po = out + ((size_t)b * Jn + w) * Cn + obase;
            float4 cur = *(const float4*)po;
            cur.x += acc[0][w] + bgv[0][0]*a0 + bgv[1][0]*a1 + bgv[2][0]*a2;
            cur.y += acc[1][w] + bgv[0][1]*a0 + bgv[1][1]*a1 + bgv[2][1]*a2;
            cur.z += acc[2][w] + bgv[0][2]*a0 + bgv[1][2]*a1 + bgv[2][2]*a2;
            cur.w += acc[3][w] + bgv[0][3]*a0 + bgv[1][3]*a1 + bgv[2][3]*a2;
            *(float4*)po = cur;
        }
    }
}

// ---------------------------------------------------------------- LN2 over C per (b,j) row; writes xn2 bf16
__global__ __launch_bounds__(256) void ln2_kernel(const float* __restrict__ X2,
        const float* __restrict__ g2, const float* __restrict__ be2,
        u16* __restrict__ xn2)
{
    int row = blockIdx.x * 4 + (threadIdx.x >> 6);
    int lane = threadIdx.x & 63;
    const float* p = X2 + (size_t)row * Cn;
    float4 v0 = ((const float4*)p)[lane];
    float4 v1 = ((const float4*)p)[lane + 64];
    float s = v0.x + v0.y + v0.z + v0.w + v1.x + v1.y + v1.z + v1.w;
    float q = v0.x*v0.x + v0.y*v0.y + v0.z*v0.z + v0.w*v0.w
            + v1.x*v1.x + v1.y*v1.y + v1.z*v1.z + v1.w*v1.w;
    #pragma unroll
    for (int off = 32; off > 0; off >>= 1) { s += __shfl_xor(s, off); q += __shfl_xor(q, off); }
    float mean = s * (1.0f / Cn);
    float var = q * (1.0f / Cn) - mean * mean;
    var = fmaxf(var, 0.f);
    float rs = rsqrtf(var + EPSf);
    float4 ga = ((const float4*)g2)[lane],      ba = ((const float4*)be2)[lane];
    float4 gb = ((const float4*)g2)[lane + 64], bb = ((const float4*)be2)[lane + 64];
    unsigned p01 = (unsigned)f2bf((v0.x-mean)*rs*ga.x + ba.x) | ((unsigned)f2bf((v0.y-mean)*rs*ga.y + ba.y) << 16);
    unsigned p23 = (unsigned)f2bf((v0.z-mean)*rs*ga.z + ba.z) | ((unsigned)f2bf((v0.w-mean)*rs*ga.w + ba.w) << 16);
    unsigned p45 = (unsigned)f2bf((v1.x-mean)*rs*gb.x + bb.x) | ((unsigned)f2bf((v1.y-mean)*rs*gb.y + bb.y) << 16);
    unsigned p67 = (unsigned)f2bf((v1.z-mean)*rs*gb.z + bb.z) | ((unsigned)f2bf((v1.w-mean)*rs*gb.w + bb.w) << 16);
    uint2 w0; w0.x = p01; w0.y = p23;
    uint2 w1; w1.x = p45; w1.y = p67;
    ((uint2*)(xn2 + (size_t)row * Cn))[lane] = w0;
    ((uint2*)(xn2 + (size_t)row * Cn))[lane + 64] = w1;
}

// ---------------------------------------------------------------- MLP2 (channel): out[row] = out[row] + gelu(xn2@W21^T+b21)@W22^T + b22
// 32 rows/block, hidden chunks of 128, fused (no H materialization)
__global__ __launch_bounds__(256) void mlp2_kernel(
    const u16* __restrict__ xn2,
    const u16* __restrict__ W21T,    // [Cn][CHn] bf16
    const float* __restrict__ b21,
    const u16* __restrict__ W22T,    // [CHn][Cn] bf16
    const float* __restrict__ b22,
    float* __restrict__ out)
{
    __shared__ u16 xsT[Cn][36];      // [c][r]
    __shared__ u16 hsT[128][36];     // [tl][r]
    int tid = threadIdx.x;
    size_t row0 = (size_t)blockIdx.x * 32;

    for (int i = 0; i < 16; ++i) {
        int idx = i * 256 + tid;                  // 4096 uint2 loads: 32r x 128 cquads
        int r = idx >> 7, cq = (idx & 127) << 2;
        uint2 u = *(const uint2*)(xn2 + (row0 + r) * Cn + cq);
        xsT[cq + 0][r] = (u16)(u.x & 0xffffu);
        xsT[cq + 1][r] = (u16)(u.x >> 16);
        xsT[cq + 2][r] = (u16)(u.y & 0xffffu);
        xsT[cq + 3][r] = (u16)(u.y >> 16);
    }
    int tq = tid & 31, rg = tid >> 5;            // phase A: t quad, row quad
    int cg = tid & 31, rq = tid >> 5;            // phase B: c group of 16, row quad
    float acc[4][16];
    #pragma unroll
    for (int j = 0; j < 4; ++j)
        #pragma unroll
        for (int i = 0; i < 16; ++i) acc[j][i] = 0.f;
    __syncthreads();

    for (int hc = 0; hc < CHn; hc += 128) {
        // phase A: pre[t=hc+tq*4+i][r=rg*4+j]
        float pre[4][4];
        {
            float bt0 = b21[hc + (tq << 2) + 0];
            float bt1 = b21[hc + (tq << 2) + 1];
            float bt2 = b21[hc + (tq << 2) + 2];
            float bt3 = b21[hc + (tq << 2) + 3];
            #pragma unroll
            for (int j = 0; j < 4; ++j) { pre[0][j] = bt0; pre[1][j] = bt1; pre[2][j] = bt2; pre[3][j] = bt3; }
        }
        const u16* wbase = W21T + hc + (tq << 2);
        #pragma unroll 4
        for (int c = 0; c < Cn; ++c) {
            uint2 wr = *(const uint2*)(wbase + (size_t)c * CHn);
            uint2 xr = *(const uint2*)&xsT[c][rg << 2];
            float w0, w1, w2, w3, x0, x1, x2, x3;
            unpack2(wr.x, w0, w1); unpack2(wr.y, w2, w3);
            unpack2(xr.x, x0, x1); unpack2(xr.y, x2, x3);
            pre[0][0] += w0*x0; pre[0][1] += w0*x1; pre[0][2] += w0*x2; pre[0][3] += w0*x3;
            pre[1][0] += w1*x0; pre[1][1] += w1*x1; pre[1][2] += w1*x2; pre[1][3] += w1*x3;
            pre[2][0] += w2*x0; pre[2][1] += w2*x1; pre[2][2] += w2*x2; pre[2][3] += w2*x3;
            pre[3][0] += w3*x0; pre[3][1] += w3*x1; pre[3][2] += w3*x2; pre[3][3] += w3*x3;
        }
        #pragma unroll
        for (int i = 0; i < 4; ++i)
            #pragma unroll
            for (int j = 0; j < 4; ++j)
                hsT[(tq << 2) + i][(rg << 2) + j] = f2bf(gelu_exact(pre[i][j]));
        __syncthreads();
        // phase B: acc[j][i] += h[r][t] * W22T[t][c]
        for (int tl = 0; tl < 128; ++tl) {
            const u16* wp = W22T + (size_t)(hc + tl) * Cn + (cg << 4);
            uint4 wa = *(const uint4*)wp;
            uint4 wb = *(const uint4*)(wp + 8);
            uint2 hr = *(const uint2*)&hsT[tl][rq << 2];
            float h0, h1, h2, h3;
            unpack2(hr.x, h0, h1); unpack2(hr.y, h2, h3);
            float w[16];
            unpack2(wa.x, w[0], w[1]); unpack2(wa.y, w[2], w[3]);
            unpack2(wa.z, w[4], w[5]); unpack2(wa.w, w[6], w[7]);
            unpack2(wb.x, w[8], w[9]); unpack2(wb.y, w[10], w[11]);
            unpack2(wb.z, w[12], w[13]); unpack2(wb.w, w[14], w[15]);
            #pragma unroll
            for (int i = 0; i < 16; ++i) {
                acc[0][i] += h0 * w[i];
                acc[1][i] += h1 * w[i];
                acc[2][i] += h2 * w[i];
                acc[3][i] += h3 * w[i];
            }
        }
        __syncthreads();
    }
    // epilogue: residual RMW + b22
    float bb[16];
    {
        float4 t0 = *(const float4*)(b22 + (cg << 4) + 0);
        float4 t1 = *(const float4*)(b22 + (cg << 4) + 4);
        float4 t2 = *(const float4*)(b22 + (cg << 4) + 8);
        float4 t3 = *(const float4*)(b22 + (cg << 4) + 12);
        bb[0]=t0.x; bb[1]=t0.y; bb[2]=t0.z; bb[3]=t0.w;
        bb[4]=t1.x; bb[5]=t1.y; bb[6]=t1.z; bb[7]=t1.w;
        bb[8]=t2.x; bb[9]=t2.y; bb[10]=t2.z; bb[11]=t2.w;
        bb[12]=t3.x; bb[13]=t3.y; bb[14]=t3.z; bb[15]=t3.w;
    }
    #pragma unroll
    for (int j = 0; j < 4; ++j) {
        size_t ro = (row0 + (rq << 2) + j) * (size_t)Cn + (cg << 4);
        float4 o0 = *(const float4*)(out + ro + 0);
        float4 o1 = *(const float4*)(out + ro + 4);
        float4 o2 = *(const float4*)(out + ro + 8);
        float4 o3 = *(const float4*)(out + ro + 12);
        o0.x += acc[j][0] + bb[0];  o0.y += acc[j][1] + bb[1];  o0.z += acc[j][2] + bb[2];  o0.w += acc[j][3] + bb[3];
        o1.x += acc[j][4] + bb[4];  o1.y += acc[j][5] + bb[5];  o1.z += acc[j][6] + bb[6];  o1.w += acc[j][7] + bb[7];
        o2.x += acc[j][8] + bb[8];  o2.y += acc[j][9] + bb[9];  o2.z += acc[j][10] + bb[10]; o2.w += acc[j][11] + bb[11];
        o3.x += acc[j][12] + bb[12]; o3.y += acc[j][13] + bb[13]; o3.z += acc[j][14] + bb[14]; o3.w += acc[j][15] + bb[15];
        *(float4*)(out + ro + 0) = o0;
        *(float4*)(out + ro + 4) = o1;
        *(float4*)(out + ro + 8) = o2;
        *(float4*)(out + ro + 12) = o3;
    }
}

// ----------------------------------------------------------------
extern "C" void kernel_launch(void* const* d_in, const int* in_sizes, int n_in,
                              void* d_out, int out_size, void* d_ws, size_t ws_size,
                              hipStream_t stream)
{
    (void)in_sizes; (void)n_in; (void)out_size; (void)ws_size;
    const float* x   = (const float*)d_in[0];
    const float* adj = (const float*)d_in[1];
    const float* g1  = (const float*)d_in[2];
    const float* be1 = (const float*)d_in[3];
    const float* g2  = (const float*)d_in[4];
    const float* be2 = (const float*)d_in[5];
    const float* Wg1 = (const float*)d_in[6];
    const float* bg1 = (const float*)d_in[7];
    const float* Wg2 = (const float*)d_in[8];
    const float* bg2 = (const float*)d_in[9];
    const float* W11 = (const float*)d_in[10];
    const float* b11 = (const float*)d_in[11];
    const float* W12 = (const float*)d_in[12];
    const float* b12 = (const float*)d_in[13];
    const float* W21 = (const float*)d_in[14];
    const float* b21 = (const float*)d_in[15];
    const float* W22 = (const float*)d_in[16];
    const float* b22 = (const float*)d_in[17];
    float* out = (float*)d_out;

    float* mean1 = (float*)d_ws;                               // B*C
    float* rstd1 = mean1 + (size_t)Bn * Cn;                    // B*C
    u16* xn2  = (u16*)(rstd1 + (size_t)Bn * Cn);               // B*J*C bf16
    u16* W21T = xn2 + (size_t)Bn * Jn * Cn;                    // CHn*Cn bf16
    u16* W22T = W21T + (size_t)CHn * Cn;                       // CHn*Cn bf16

    prep_wT<<<512, 256, 0, stream>>>(W21, W22, W21T, W22T);
    ln1_stats<<<(Bn * Cn) / 256, 256, 0, stream>>>(x, mean1, rstd1);
    mlp1_kernel<<<(Bn * Cn) / 1024, 256, 0, stream>>>(x, mean1, rstd1, g1, be1, W11, b11, W12, b12, out);
    gcn_kernel<1><<<2048, 256, 0, stream>>>(x, (const u16*)nullptr, mean1, rstd1, g1, be1, Wg1, bg1, adj, out);
    ln2_kernel<<<(Bn * Jn) / 4, 256, 0, stream>>>(out, g2, be2, xn2);
    mlp2_kernel<<<(Bn * Jn) / 32, 256, 0, stream>>>(xn2, W21T, b21, W22T, b22, out);
    gcn_kernel<2><<<2048, 256, 0, stream>>>((const float*)nullptr, xn2, nullptr, nullptr, nullptr, nullptr, Wg2, bg2, adj, out);
}

// Round 2
// 2668.043 us; speedup vs baseline: 6.4580x; 6.4580x over previous
//
#include <hip/hip_runtime.h>
#include <hip/hip_bf16.h>

#define Bn   4096
#define Jn   17
#define Cn   512
#define Kn   3
#define TOKn 256
#define CHn  2048
#define EPSf 1e-5f
#define Mrows (Bn * Jn)          // 69632 GEMM rows

typedef unsigned short u16;
typedef short bf8_t __attribute__((ext_vector_type(8)));
typedef float f32x4 __attribute__((ext_vector_type(4)));

__device__ __forceinline__ float gelu_exact(float x) {
    return 0.5f * x * (1.0f + erff(x * 0.70710678118654752440f));
}
__device__ __forceinline__ float bf2f(u16 u) {
    union { float f; unsigned int i; } w; w.i = ((unsigned int)u) << 16; return w.f;
}
__device__ __forceinline__ u16 f2bf(float f) {
    union { float f; unsigned int i; } w; w.f = f;
    unsigned int x = w.i;
    return (u16)((x + 0x7fffu + ((x >> 16) & 1u)) >> 16);
}
__device__ __forceinline__ unsigned pk2(float a, float b) {
    return (unsigned)f2bf(a) | ((unsigned)f2bf(b) << 16);
}
__device__ __forceinline__ void unpack2(unsigned u, float& a, float& b) {
    union { float f; unsigned int i; } t;
    t.i = u << 16;          a = t.f;
    t.i = u & 0xffff0000u;  b = t.f;
}
__device__ __forceinline__ void gload_lds16(const void* g, void* l) {
    __builtin_amdgcn_global_load_lds(
        (const __attribute__((address_space(1))) void*)g,
        (__attribute__((address_space(3))) void*)l, 16, 0, 0);
}

// ---------------------------------------------------------------- prep: bf16 casts + Wg permute + bias2 tables
__global__ __launch_bounds__(256) void prep_kernel(
    const float* __restrict__ W21, const float* __restrict__ W22,
    const float* __restrict__ Wg1, const float* __restrict__ Wg2,
    const float* __restrict__ bg1, const float* __restrict__ bg2,
    const float* __restrict__ adj,
    u16* __restrict__ W21b, u16* __restrict__ W22b,
    u16* __restrict__ Wg1t, u16* __restrict__ Wg2t,
    float* __restrict__ bias2a, float* __restrict__ bias2b)
{
    int bid = blockIdx.x, tid = threadIdx.x;
    if (bid < 1024) {
        const float* src = (bid < 512) ? W21 : W22;
        u16* dst = (bid < 512) ? W21b : W22b;
        size_t base = (size_t)(bid & 511) * 2048 + (size_t)tid * 8;
        float4 v0 = *(const float4*)(src + base);
        float4 v1 = *(const float4*)(src + base + 4);
        uint4 o;
        o.x = pk2(v0.x, v0.y); o.y = pk2(v0.z, v0.w);
        o.z = pk2(v1.x, v1.y); o.w = pk2(v1.z, v1.w);
        *(uint4*)(dst + base) = o;
    } else if (bid < 2048) {
        const float* src = (bid < 1536) ? Wg1 : Wg2;
        u16* dst = (bid < 1536) ? Wg1t : Wg2t;
        int rbase = ((bid - 1024) & 511) * 3;
        int c = tid * 2;
        for (int rr = 0; rr < 3; ++rr) {
            int ro = rbase + rr;                  // over (k,o)
            int k = ro >> 9, o = ro & 511;
            const float* sp = src + ((size_t)k * Cn + o) * Cn + c;
            float2 v = *(const float2*)sp;
            *(unsigned*)(dst + (size_t)o * (Kn * Cn) + k * Cn + c) = pk2(v.x, v.y);
        }
    } else {
        __shared__ float adjcs[Kn][Jn];
        for (int i = tid; i < Kn * Jn; i += 256) {
            int k = i / Jn, w = i - k * Jn;
            float s = 0.f;
            for (int v = 0; v < Jn; ++v) s += adj[k * (Jn * Jn) + v * Jn + w];
            adjcs[k][w] = s;
        }
        __syncthreads();
        for (int i = tid; i < Jn * Cn; i += 256) {
            int w = i >> 9, o = i & 511;
            float sa = 0.f, sb = 0.f;
            #pragma unroll
            for (int k = 0; k < Kn; ++k) {
                sa += bg1[k * Cn + o] * adjcs[k][w];
                sb += bg2[k * Cn + o] * adjcs[k][w];
            }
            bias2a[i] = sa; bias2b[i] = sb;
        }
    }
}

// ---------------------------------------------------------------- premix: (optional LN1) + adjacency mix -> xmix[(b,w)][k*512+c] bf16
template<int STAGE>
__global__ __launch_bounds__(256) void premix_kernel(
    const float* __restrict__ x,          // stage1
    const u16* __restrict__ xn2,          // stage2
    const float* __restrict__ adj,
    const float* __restrict__ g1, const float* __restrict__ be1,
    float* __restrict__ mean1, float* __restrict__ rstd1,
    u16* __restrict__ xmix)
{
    __shared__ float xsh[Jn][Cn];         // 34 KB
    __shared__ float coef[Kn][Jn][Jn];    // [k][w][v] (stage1: *g1[v])
    __shared__ float s0sh[Kn][Jn];        // sum_v adj*be1
    __shared__ float s1sh[Kn][Jn];        // sum_v coef
    __shared__ float msh[Cn], rsh[Cn];
    int b = blockIdx.x, tid = threadIdx.x;

    for (int i = tid; i < Kn * Jn * Jn; i += 256) {
        int k = i / (Jn * Jn); int rem = i - k * (Jn * Jn);
        int v = rem / Jn; int w = rem - v * Jn;
        float av = adj[i];
        coef[k][w][v] = (STAGE == 1) ? av * g1[v] : av;
    }
    if (STAGE == 1) {
        const float* xp = x + (size_t)b * (Jn * Cn);
        for (int i = tid; i < (Jn * Cn) / 4; i += 256)
            ((float4*)&xsh[0][0])[i] = ((const float4*)xp)[i];
    } else {
        const u16* xp = xn2 + (size_t)b * (Jn * Cn);
        for (int i = tid; i < (Jn * Cn) / 8; i += 256) {
            uint4 u = ((const uint4*)xp)[i];
            float* d = &(&xsh[0][0])[i * 8];
            unpack2(u.x, d[0], d[1]); unpack2(u.y, d[2], d[3]);
            unpack2(u.z, d[4], d[5]); unpack2(u.w, d[6], d[7]);
        }
    }
    __syncthreads();
    if (STAGE == 1) {
        for (int c = tid; c < Cn; c += 256) {
            float s = 0.f, q = 0.f;
            #pragma unroll
            for (int v = 0; v < Jn; ++v) { float t = xsh[v][c]; s += t; q += t * t; }
            float m = s * (1.0f / Jn);
            float var = fmaxf(q * (1.0f / Jn) - m * m, 0.f);
            float r = rsqrtf(var + EPSf);
            msh[c] = m; rsh[c] = r;
            mean1[(size_t)b * Cn + c] = m;
            rstd1[(size_t)b * Cn + c] = r;
        }
    }
    if (tid < Kn * Jn) {
        int k = tid / Jn, w = tid - k * Jn;
        float s0 = 0.f, s1 = 0.f;
        #pragma unroll
        for (int v = 0; v < Jn; ++v) {
            if (STAGE == 1) s0 += adj[k * (Jn * Jn) + v * Jn + w] * be1[v];
            s1 += coef[k][w][v];
        }
        s0sh[k][w] = s0; s1sh[k][w] = s1;
    }
    __syncthreads();
    u16* orow = xmix + (size_t)b * Jn * (Kn * Cn);
    for (int k = 0; k < Kn; ++k)
        for (int w = 0; w < Jn; ++w) {
            float cf[Jn];
            #pragma unroll
            for (int v = 0; v < Jn; ++v) cf[v] = coef[k][w][v];
            float ss1 = s1sh[k][w], ss0 = s0sh[k][w];
            for (int c = tid; c < Cn; c += 256) {
                float dot = 0.f;
                #pragma unroll
                for (int v = 0; v < Jn; ++v) dot += cf[v] * xsh[v][c];
                float val;
                if (STAGE == 1) val = rsh[c] * (dot - msh[c] * ss1) + ss0;
                else            val = dot;
                orow[(size_t)w * (Kn * Cn) + k * Cn + c] = f2bf(val);
            }
        }
}

// ---------------------------------------------------------------- MLP1 (token mix), fp32 VALU (unchanged from R1)
__global__ __launch_bounds__(256) void mlp1_kernel(
    const float* __restrict__ x, const float* __restrict__ mean1, const float* __restrict__ rstd1,
    const float* __restrict__ g1, const float* __restrict__ be1,
    const float* __restrict__ W11, const float* __restrict__ b11,
    const float* __restrict__ W12, const float* __restrict__ b12,
    float* __restrict__ out)
{
    __shared__ float sW11[TOKn][20];
    __shared__ float sW12T[TOKn][20];
    __shared__ float sb11[TOKn];
    int tid = threadIdx.x;
    for (int idx = tid; idx < TOKn * Jn; idx += 256) {
        int t = idx / Jn, j = idx - t * Jn;
        sW11[t][j] = W11[idx];
    }
    for (int idx = tid; idx < Jn * TOKn; idx += 256) {
        int j = idx >> 8, t = idx & 255;
        sW12T[t][j] = W12[idx];
    }
    if (tid < TOKn) sb11[tid] = b11[tid];
    __syncthreads();

    int rowb = blockIdx.x * 1024 + (tid << 2);
    int b = rowb >> 9;
    int c0v = rowb & 511;
    const float* px = x + (size_t)b * (Jn * Cn) + c0v;
    float4 mv = *(const float4*)(mean1 + rowb);
    float4 rv = *(const float4*)(rstd1 + rowb);
    float xn[4][Jn];
    #pragma unroll
    for (int j = 0; j < Jn; ++j) {
        float4 xv = *(const float4*)(px + j * Cn);
        float gj = g1[j], bj = be1[j];
        xn[0][j] = (xv.x - mv.x) * rv.x * gj + bj;
        xn[1][j] = (xv.y - mv.y) * rv.y * gj + bj;
        xn[2][j] = (xv.z - mv.z) * rv.z * gj + bj;
        xn[3][j] = (xv.w - mv.w) * rv.w * gj + bj;
    }
    float acc[4][Jn];
    #pragma unroll
    for (int i = 0; i < 4; ++i)
        #pragma unroll
        for (int j = 0; j < Jn; ++j) acc[i][j] = 0.f;

    for (int t = 0; t < TOKn; ++t) {
        float4 wa = *(const float4*)&sW11[t][0];
        float4 wb = *(const float4*)&sW11[t][4];
        float4 wc = *(const float4*)&sW11[t][8];
        float4 wd = *(const float4*)&sW11[t][12];
        float we = sW11[t][16];
        float bt = sb11[t];
        float h[4];
        #pragma unroll
        for (int i = 0; i < 4; ++i) {
            float pre = bt
              + xn[i][0]*wa.x + xn[i][1]*wa.y + xn[i][2]*wa.z + xn[i][3]*wa.w
              + xn[i][4]*wb.x + xn[i][5]*wb.y + xn[i][6]*wb.z + xn[i][7]*wb.w
              + xn[i][8]*wc.x + xn[i][9]*wc.y + xn[i][10]*wc.z + xn[i][11]*wc.w
              + xn[i][12]*wd.x + xn[i][13]*wd.y + xn[i][14]*wd.z + xn[i][15]*wd.w
              + xn[i][16]*we;
            h[i] = gelu_exact(pre);
        }
        float4 va = *(const float4*)&sW12T[t][0];
        float4 vb = *(const float4*)&sW12T[t][4];
        float4 vc = *(const float4*)&sW12T[t][8];
        float4 vd = *(const float4*)&sW12T[t][12];
        float ve = sW12T[t][16];
        #pragma unroll
        for (int i = 0; i < 4; ++i) {
            acc[i][0]  += h[i]*va.x; acc[i][1]  += h[i]*va.y; acc[i][2]  += h[i]*va.z; acc[i][3]  += h[i]*va.w;
            acc[i][4]  += h[i]*vb.x; acc[i][5]  += h[i]*vb.y; acc[i][6]  += h[i]*vb.z; acc[i][7]  += h[i]*vb.w;
            acc[i][8]  += h[i]*vc.x; acc[i][9]  += h[i]*vc.y; acc[i][10] += h[i]*vc.z; acc[i][11] += h[i]*vc.w;
            acc[i][12] += h[i]*vd.x; acc[i][13] += h[i]*vd.y; acc[i][14] += h[i]*vd.z; acc[i][15] += h[i]*vd.w;
            acc[i][16] += h[i]*ve;
        }
    }
    #pragma unroll
    for (int j = 0; j < Jn; ++j) {
        float4 xv = *(const float4*)(px + j * Cn);
        float bj = b12[j];
        float4 o;
        o.x = xv.x + acc[0][j] + bj;
        o.y = xv.y + acc[1][j] + bj;
        o.z = xv.z + acc[2][j] + bj;
        o.w = xv.w + acc[3][j] + bj;
        *(float4*)(out + (size_t)b * (Jn * Cn) + (size_t)j * Cn + c0v) = o;
    }
}

// ---------------------------------------------------------------- LN2 over C per (b,j) row; writes xn2 bf16 (unchanged from R1)
__global__ __launch_bounds__(256) void ln2_kernel(const float* __restrict__ X2,
        const float* __restrict__ g2, const float* __restrict__ be2,
        u16* __restrict__ xn2)
{
    int row = blockIdx.x * 4 + (threadIdx.x >> 6);
    int lane = threadIdx.x & 63;
    const float* p = X2 + (size_t)row * Cn;
    float4 v0 = ((const float4*)p)[lane];
    float4 v1 = ((const float4*)p)[lane + 64];
    float s = v0.x + v0.y + v0.z + v0.w + v1.x + v1.y + v1.z + v1.w;
    float q = v0.x*v0.x + v0.y*v0.y + v0.z*v0.z + v0.w*v0.w
            + v1.x*v1.x + v1.y*v1.y + v1.z*v1.z + v1.w*v1.w;
    #pragma unroll
    for (int off = 32; off > 0; off >>= 1) { s += __shfl_xor(s, off); q += __shfl_xor(q, off); }
    float mean = s * (1.0f / Cn);
    float var = fmaxf(q * (1.0f / Cn) - mean * mean, 0.f);
    float rs = rsqrtf(var + EPSf);
    float4 ga = ((const float4*)g2)[lane],      ba = ((const float4*)be2)[lane];
    float4 gb = ((const float4*)g2)[lane + 64], bb = ((const float4*)be2)[lane + 64];
    uint2 w0, w1;
    w0.x = pk2((v0.x-mean)*rs*ga.x + ba.x, (v0.y-mean)*rs*ga.y + ba.y);
    w0.y = pk2((v0.z-mean)*rs*ga.z + ba.z, (v0.w-mean)*rs*ga.w + ba.w);
    w1.x = pk2((v1.x-mean)*rs*gb.x + bb.x, (v1.y-mean)*rs*gb.y + bb.y);
    w1.y = pk2((v1.z-mean)*rs*gb.z + bb.z, (v1.w-mean)*rs*gb.w + bb.w);
    ((uint2*)(xn2 + (size_t)row * Cn))[lane] = w0;
    ((uint2*)(xn2 + (size_t)row * Cn))[lane + 64] = w1;
}

// ---------------------------------------------------------------- MFMA GEMM: C(M x N) = A(M x K) * Bt(N x K)^T
// 128x128 tile, BK=32, 4 waves (2x2), 16x16x32 bf16 MFMA, dbuf LDS, chunk-XOR swizzle.
// EPI 0: outH = bf16(gelu(acc + bias[col]))    (ld Nld)
// EPI 1: outF += acc + (bias ? bias[col] : 0)  (ld Nld)
// EPI 2: outF += acc + bias[(row%17)*512+col]  (ld Nld)
template<int EPI>
__global__ __launch_bounds__(256) void gemm_bt(
    const u16* __restrict__ A, int ldA,
    const u16* __restrict__ Bt, int ldB,
    int K, int Nld,
    const float* __restrict__ bias,
    float* __restrict__ outF, u16* __restrict__ outH)
{
    __shared__ __align__(16) u16 As[2][128 * 32];
    __shared__ __align__(16) u16 Bs[2][128 * 32];
    int tid = threadIdx.x;
    int m0 = blockIdx.x * 128;
    int n0 = blockIdx.y * 128;
    int wave = tid >> 6, lane = tid & 63;
    int wr = wave >> 1, wc = wave & 1;

    // staging source pointers (2 chunks per matrix per thread), swizzle cs = ci ^ ((r>>1)&3)
    const u16* aSrc[2]; const u16* bSrc[2];
    #pragma unroll
    for (int t = 0; t < 2; ++t) {
        int idx = t * 256 + tid;
        int r = idx >> 2;
        int cs = (idx & 3) ^ ((r >> 1) & 3);
        aSrc[t] = A  + (size_t)(m0 + r) * ldA + cs * 8;
        bSrc[t] = Bt + (size_t)(n0 + r) * ldB + cs * 8;
    }
    // fragment LDS byte offsets (read side of the same swizzle)
    int aOff[4], bOff[4];
    #pragma unroll
    for (int i = 0; i < 4; ++i) {
        int ra = wr * 64 + i * 16 + (lane & 15);
        aOff[i] = ra * 64 + ((((lane >> 4)) ^ ((ra >> 1) & 3)) << 4);
        int rb = wc * 64 + i * 16 + (lane & 15);
        bOff[i] = rb * 64 + ((((lane >> 4)) ^ ((rb >> 1) & 3)) << 4);
    }

    f32x4 acc[4][4];
    #pragma unroll
    for (int i = 0; i < 4; ++i)
        #pragma unroll
        for (int j = 0; j < 4; ++j) acc[i][j] = (f32x4)0.f;

    int KT = K >> 5;
    // prologue stage
    #pragma unroll
    for (int t = 0; t < 2; ++t) {
        int idx = t * 256 + tid;
        gload_lds16(aSrc[t], (char*)&As[0][0] + idx * 16);
        gload_lds16(bSrc[t], (char*)&Bs[0][0] + idx * 16);
    }
    int cur = 0;
    for (int kt = 0; kt < KT; ++kt) {
        asm volatile("s_waitcnt vmcnt(0)" ::: "memory");
        __syncthreads();
        if (kt + 1 < KT) {
            int k0 = (kt + 1) << 5;
            #pragma unroll
            for (int t = 0; t < 2; ++t) {
                int idx = t * 256 + tid;
                gload_lds16(aSrc[t] + k0, (char*)&As[cur ^ 1][0] + idx * 16);
                gload_lds16(bSrc[t] + k0, (char*)&Bs[cur ^ 1][0] + idx * 16);
            }
        }
        bf8_t af[4], bfr[4];
        #pragma unroll
        for (int i = 0; i < 4; ++i) {
            af[i]  = *(const bf8_t*)((const char*)&As[cur][0] + aOff[i]);
            bfr[i] = *(const bf8_t*)((const char*)&Bs[cur][0] + bOff[i]);
        }
        #pragma unroll
        for (int mi = 0; mi < 4; ++mi)
            #pragma unroll
            for (int ni = 0; ni < 4; ++ni)
                acc[mi][ni] = __builtin_amdgcn_mfma_f32_16x16x32_bf16(af[mi], bfr[ni], acc[mi][ni], 0, 0, 0);
        cur ^= 1;
    }

    // epilogue: D[row=(lane>>4)*4+i][col=lane&15] per 16x16 frag
    #pragma unroll
    for (int mi = 0; mi < 4; ++mi) {
        int rbase = m0 + wr * 64 + mi * 16 + ((lane >> 4) << 2);
        #pragma unroll
        for (int ni = 0; ni < 4; ++ni) {
            int col = n0 + wc * 64 + ni * 16 + (lane & 15);
            if (EPI == 0) {
                float bv = bias[col];
                #pragma unroll
                for (int i = 0; i < 4; ++i) {
                    float v = gelu_exact(acc[mi][ni][i] + bv);
                    outH[(size_t)(rbase + i) * Nld + col] = f2bf(v);
                }
            } else if (EPI == 1) {
                float bv = bias ? bias[col] : 0.f;
                #pragma unroll
                for (int i = 0; i < 4; ++i) {
                    size_t off = (size_t)(rbase + i) * Nld + col;
                    outF[off] += acc[mi][ni][i] + bv;
                }
            } else {
                #pragma unroll
                for (int i = 0; i < 4; ++i) {
                    int row = rbase + i;
                    int w = row % Jn;
                    size_t off = (size_t)row * Nld + col;
                    outF[off] += acc[mi][ni][i] + bias[w * Cn + col];
                }
            }
        }
    }
}

// ----------------------------------------------------------------
extern "C" void kernel_launch(void* const* d_in, const int* in_sizes, int n_in,
                              void* d_out, int out_size, void* d_ws, size_t ws_size,
                              hipStream_t stream)
{
    (void)in_sizes; (void)n_in; (void)out_size; (void)ws_size;
    const float* x   = (const float*)d_in[0];
    const float* adj = (const float*)d_in[1];
    const float* g1  = (const float*)d_in[2];
    const float* be1 = (const float*)d_in[3];
    const float* g2  = (const float*)d_in[4];
    const float* be2 = (const float*)d_in[5];
    const float* Wg1 = (const float*)d_in[6];
    const float* bg1 = (const float*)d_in[7];
    const float* Wg2 = (const float*)d_in[8];
    const float* bg2 = (const float*)d_in[9];
    const float* W11 = (const float*)d_in[10];
    const float* b11 = (const float*)d_in[11];
    const float* W12 = (const float*)d_in[12];
    const float* b12 = (const float*)d_in[13];
    const float* W21 = (const float*)d_in[14];
    const float* b21 = (const float*)d_in[15];
    const float* W22 = (const float*)d_in[16];
    const float* b22 = (const float*)d_in[17];
    float* out = (float*)d_out;

    // ws layout (bytes, all 16B-aligned)
    char* p = (char*)d_ws;
    float* mean1  = (float*)p;                 p += (size_t)Bn * Cn * 4;
    float* rstd1  = (float*)p;                 p += (size_t)Bn * Cn * 4;
    u16*   xn2    = (u16*)p;                   p += (size_t)Mrows * Cn * 2;
    u16*   W21b   = (u16*)p;                   p += (size_t)CHn * Cn * 2;
    u16*   W22b   = (u16*)p;                   p += (size_t)CHn * Cn * 2;
    u16*   Wg1t   = (u16*)p;                   p += (size_t)Cn * Kn * Cn * 2;
    u16*   Wg2t   = (u16*)p;                   p += (size_t)Cn * Kn * Cn * 2;
    float* bias2a = (float*)p;                 p += (size_t)Jn * Cn * 4;
    float* bias2b = (float*)p;                 p += (size_t)Jn * Cn * 4;
    u16*   xmix   = (u16*)p;                   // max(69632*1536, 69632*1024)*2 = 213.9 MB (shared with H)
    u16*   Hbuf   = xmix;

    prep_kernel<<<2049, 256, 0, stream>>>(W21, W22, Wg1, Wg2, bg1, bg2, adj,
                                          W21b, W22b, Wg1t, Wg2t, bias2a, bias2b);
    // stage 1
    premix_kernel<1><<<Bn, 256, 0, stream>>>(x, (const u16*)nullptr, adj, g1, be1, mean1, rstd1, xmix);
    mlp1_kernel<<<(Bn * Cn) / 1024, 256, 0, stream>>>(x, mean1, rstd1, g1, be1, W11, b11, W12, b12, out);
    {
        dim3 g(Mrows / 128, Cn / 128);
        gemm_bt<2><<<g, 256, 0, stream>>>(xmix, Kn * Cn, Wg1t, Kn * Cn, Kn * Cn, Cn, bias2a, out, (u16*)nullptr);
    }
    // stage 2
    ln2_kernel<<<Mrows / 4, 256, 0, stream>>>(out, g2, be2, xn2);
    for (int h = 0; h < 2; ++h) {
        int hc = h * 1024;
        dim3 ga(Mrows / 128, 1024 / 128);
        gemm_bt<0><<<ga, 256, 0, stream>>>(xn2, Cn, W21b + (size_t)hc * Cn, Cn, Cn, 1024, b21 + hc, (float*)nullptr, Hbuf);
        dim3 gb(Mrows / 128, Cn / 128);
        gemm_bt<1><<<gb, 256, 0, stream>>>(Hbuf, 1024, W22b + hc, CHn, 1024, Cn, (h == 0) ? b22 : (const float*)nullptr, out, (u16*)nullptr);
    }
    premix_kernel<2><<<Bn, 256, 0, stream>>>((const float*)nullptr, xn2, adj, (const float*)nullptr, (const float*)nullptr,
                                             (float*)nullptr, (float*)nullptr, xmix);
    {
        dim3 g(Mrows / 128, Cn / 128);
        gemm_bt<2><<<g, 256, 0, stream>>>(xmix, Kn * Cn, Wg2t, Kn * Cn, Kn * Cn, Cn, bias2b, out, (u16*)nullptr);
    }
}

// Round 3
// 2456.756 us; speedup vs baseline: 7.0134x; 1.0860x over previous
//
#include <hip/hip_runtime.h>
#include <hip/hip_bf16.h>

#define Bn   4096
#define Jn   17
#define Cn   512
#define Kn   3
#define TOKn 256
#define CHn  2048
#define EPSf 1e-5f
#define Mrows (Bn * Jn)          // 69632 GEMM rows

typedef unsigned short u16;
typedef short bf8_t __attribute__((ext_vector_type(8)));
typedef float f32x4 __attribute__((ext_vector_type(4)));

__device__ __forceinline__ float gelu_exact(float x) {
    return 0.5f * x * (1.0f + erff(x * 0.70710678118654752440f));
}
__device__ __forceinline__ float bf2f(u16 u) {
    union { float f; unsigned int i; } w; w.i = ((unsigned int)u) << 16; return w.f;
}
__device__ __forceinline__ u16 f2bf(float f) {
    union { float f; unsigned int i; } w; w.f = f;
    unsigned int x = w.i;
    return (u16)((x + 0x7fffu + ((x >> 16) & 1u)) >> 16);
}
__device__ __forceinline__ unsigned pk2(float a, float b) {
    return (unsigned)f2bf(a) | ((unsigned)f2bf(b) << 16);
}
__device__ __forceinline__ void unpack2(unsigned u, float& a, float& b) {
    union { float f; unsigned int i; } t;
    t.i = u << 16;          a = t.f;
    t.i = u & 0xffff0000u;  b = t.f;
}
__device__ __forceinline__ void gload_lds16(const void* g, void* l) {
    __builtin_amdgcn_global_load_lds(
        (const __attribute__((address_space(1))) void*)g,
        (__attribute__((address_space(3))) void*)l, 16, 0, 0);
}

// ---------------------------------------------------------------- prep: bf16 casts + Wg permute + bias2 tables + mlp1 padded weights
__global__ __launch_bounds__(256) void prep_kernel(
    const float* __restrict__ W21, const float* __restrict__ W22,
    const float* __restrict__ Wg1, const float* __restrict__ Wg2,
    const float* __restrict__ bg1, const float* __restrict__ bg2,
    const float* __restrict__ adj,
    const float* __restrict__ W11, const float* __restrict__ W12,
    u16* __restrict__ W21b, u16* __restrict__ W22b,
    u16* __restrict__ Wg1t, u16* __restrict__ Wg2t,
    float* __restrict__ bias2a, float* __restrict__ bias2b,
    u16* __restrict__ W11p, u16* __restrict__ W12p)
{
    int bid = blockIdx.x, tid = threadIdx.x;
    if (bid < 1024) {
        const float* src = (bid < 512) ? W21 : W22;
        u16* dst = (bid < 512) ? W21b : W22b;
        size_t base = (size_t)(bid & 511) * 2048 + (size_t)tid * 8;
        float4 v0 = *(const float4*)(src + base);
        float4 v1 = *(const float4*)(src + base + 4);
        uint4 o;
        o.x = pk2(v0.x, v0.y); o.y = pk2(v0.z, v0.w);
        o.z = pk2(v1.x, v1.y); o.w = pk2(v1.z, v1.w);
        *(uint4*)(dst + base) = o;
    } else if (bid < 2048) {
        const float* src = (bid < 1536) ? Wg1 : Wg2;
        u16* dst = (bid < 1536) ? Wg1t : Wg2t;
        int rbase = ((bid - 1024) & 511) * 3;
        int c = tid * 2;
        for (int rr = 0; rr < 3; ++rr) {
            int ro = rbase + rr;                  // over (k,o)
            int k = ro >> 9, o = ro & 511;
            const float* sp = src + ((size_t)k * Cn + o) * Cn + c;
            float2 v = *(const float2*)sp;
            *(unsigned*)(dst + (size_t)o * (Kn * Cn) + k * Cn + c) = pk2(v.x, v.y);
        }
    } else if (bid == 2048) {
        __shared__ float adjcs[Kn][Jn];
        for (int i = tid; i < Kn * Jn; i += 256) {
            int k = i / Jn, w = i - k * Jn;
            float s = 0.f;
            for (int v = 0; v < Jn; ++v) s += adj[k * (Jn * Jn) + v * Jn + w];
            adjcs[k][w] = s;
        }
        __syncthreads();
        for (int i = tid; i < Jn * Cn; i += 256) {
            int w = i >> 9, o = i & 511;
            float sa = 0.f, sb = 0.f;
            #pragma unroll
            for (int k = 0; k < Kn; ++k) {
                sa += bg1[k * Cn + o] * adjcs[k][w];
                sb += bg2[k * Cn + o] * adjcs[k][w];
            }
            bias2a[i] = sa; bias2b[i] = sb;
        }
    } else {
        // W11p [256][32] (pad j>=17 with 0), W12p [32][256] (pad j>=17 rows with 0)
        for (int idx = tid; idx < TOKn * 32; idx += 256) {
            int t = idx >> 5, k = idx & 31;
            W11p[idx] = (k < Jn) ? f2bf(W11[t * Jn + k]) : (u16)0;
        }
        for (int idx = tid; idx < 32 * TOKn; idx += 256) {
            int j = idx >> 8, t = idx & 255;
            W12p[idx] = (j < Jn) ? f2bf(W12[j * TOKn + t]) : (u16)0;
        }
    }
}

// ---------------------------------------------------------------- premix: (optional LN1) + adjacency mix -> xmix[(b,w)][k*512+c] bf16
template<int STAGE>
__global__ __launch_bounds__(256) void premix_kernel(
    const float* __restrict__ x,          // stage1
    const u16* __restrict__ xn2,          // stage2
    const float* __restrict__ adj,
    const float* __restrict__ g1, const float* __restrict__ be1,
    float* __restrict__ mean1, float* __restrict__ rstd1,
    u16* __restrict__ xmix)
{
    __shared__ float xsh[Jn][Cn];         // 34 KB
    __shared__ float coef[Kn][Jn][Jn];    // [k][w][v] (stage1: *g1[v])
    __shared__ float s0sh[Kn][Jn];        // sum_v adj*be1
    __shared__ float s1sh[Kn][Jn];        // sum_v coef
    __shared__ float msh[Cn], rsh[Cn];
    int b = blockIdx.x, tid = threadIdx.x;

    for (int i = tid; i < Kn * Jn * Jn; i += 256) {
        int k = i / (Jn * Jn); int rem = i - k * (Jn * Jn);
        int v = rem / Jn; int w = rem - v * Jn;
        float av = adj[i];
        coef[k][w][v] = (STAGE == 1) ? av * g1[v] : av;
    }
    if (STAGE == 1) {
        const float* xp = x + (size_t)b * (Jn * Cn);
        for (int i = tid; i < (Jn * Cn) / 4; i += 256)
            ((float4*)&xsh[0][0])[i] = ((const float4*)xp)[i];
    } else {
        const u16* xp = xn2 + (size_t)b * (Jn * Cn);
        for (int i = tid; i < (Jn * Cn) / 8; i += 256) {
            uint4 u = ((const uint4*)xp)[i];
            float* d = &(&xsh[0][0])[i * 8];
            unpack2(u.x, d[0], d[1]); unpack2(u.y, d[2], d[3]);
            unpack2(u.z, d[4], d[5]); unpack2(u.w, d[6], d[7]);
        }
    }
    __syncthreads();
    if (STAGE == 1) {
        for (int c = tid; c < Cn; c += 256) {
            float s = 0.f, q = 0.f;
            #pragma unroll
            for (int v = 0; v < Jn; ++v) { float t = xsh[v][c]; s += t; q += t * t; }
            float m = s * (1.0f / Jn);
            float var = fmaxf(q * (1.0f / Jn) - m * m, 0.f);
            float r = rsqrtf(var + EPSf);
            msh[c] = m; rsh[c] = r;
            mean1[(size_t)b * Cn + c] = m;
            rstd1[(size_t)b * Cn + c] = r;
        }
    }
    if (tid < Kn * Jn) {
        int k = tid / Jn, w = tid - k * Jn;
        float s0 = 0.f, s1 = 0.f;
        #pragma unroll
        for (int v = 0; v < Jn; ++v) {
            if (STAGE == 1) s0 += adj[k * (Jn * Jn) + v * Jn + w] * be1[v];
            s1 += coef[k][w][v];
        }
        s0sh[k][w] = s0; s1sh[k][w] = s1;
    }
    __syncthreads();
    u16* orow = xmix + (size_t)b * Jn * (Kn * Cn);
    for (int k = 0; k < Kn; ++k)
        for (int w = 0; w < Jn; ++w) {
            float cf[Jn];
            #pragma unroll
            for (int v = 0; v < Jn; ++v) cf[v] = coef[k][w][v];
            float ss1 = s1sh[k][w], ss0 = s0sh[k][w];
            for (int c = tid; c < Cn; c += 256) {
                float dot = 0.f;
                #pragma unroll
                for (int v = 0; v < Jn; ++v) dot += cf[v] * xsh[v][c];
                float val;
                if (STAGE == 1) val = rsh[c] * (dot - msh[c] * ss1) + ss0;
                else            val = dot;
                orow[(size_t)w * (Kn * Cn) + k * Cn + c] = f2bf(val);
            }
        }
}

// ---------------------------------------------------------------- MLP1 (token mix) via MFMA
// block = (b, 128-chunk of c). GEMM1: H=gelu(xn@W11p^T) K=32; GEMM2: out = x + W12p@H^T + b12, K=256.
// Hidden processed in 2 chunks of 128; each wave owns 32 c-rows end-to-end (no inter-wave barriers after As).
__global__ __launch_bounds__(256) void mlp1_mfma(
    const float* __restrict__ x,
    const float* __restrict__ mean1, const float* __restrict__ rstd1,
    const float* __restrict__ g1, const float* __restrict__ be1,
    const u16* __restrict__ W11p,   // [256][32] bf16 padded
    const float* __restrict__ b11,
    const u16* __restrict__ W12p,   // [32][256] bf16 padded
    const float* __restrict__ b12,
    float* __restrict__ out)
{
    __shared__ __align__(16) u16 As[128 * 32];     // xn tile, chunk-swizzled
    __shared__ __align__(16) u16 Hs[128 * 128];    // hidden chunk, chunk-swizzled
    __shared__ __align__(16) u16 W11s[TOKn * 32];  // swizzled
    __shared__ __align__(16) u16 W12s[32 * TOKn];  // swizzled
    __shared__ __align__(16) float b11s[TOKn];
    __shared__ __align__(16) float msrs[256];      // [0:128)=mean, [128:256)=rstd
    __shared__ float g1s[32], be1s[32];

    int tid = threadIdx.x;
    int lane = tid & 63, wave = tid >> 6;
    int b = blockIdx.y, c0 = blockIdx.x * 128;
    const float* xb = x + (size_t)b * (Jn * Cn);

    // ---- stage (all dests wave-linear for global_load_lds)
    #pragma unroll
    for (int t = 0; t < 4; ++t) {          // W11s: 1024 x 16B, src chunk s^(row&3)
        int idx = t * 256 + tid;
        int tt = idx >> 2, s = idx & 3;
        gload_lds16(W11p + tt * 32 + ((s ^ (tt & 3)) << 3), (char*)W11s + idx * 16);
    }
    #pragma unroll
    for (int t = 0; t < 4; ++t) {          // W12s: 1024 x 16B, src chunk s^(row&7)
        int idx = t * 256 + tid;
        int j = idx >> 5, s = idx & 31;
        gload_lds16(W12p + j * TOKn + ((s ^ (j & 7)) << 3), (char*)W12s + idx * 16);
    }
    if (wave == 0) gload_lds16(b11 + lane * 4, (char*)b11s + lane * 16);
    if (wave == 1) {
        const float* src = (lane < 32) ? (mean1 + (size_t)b * Cn + c0 + lane * 4)
                                       : (rstd1 + (size_t)b * Cn + c0 + (lane - 32) * 4);
        gload_lds16(src, (char*)msrs + lane * 16);
    }
    if (tid < Jn) { g1s[tid] = g1[tid]; be1s[tid] = be1[tid]; }
    asm volatile("s_waitcnt vmcnt(0)" ::: "memory");
    __syncthreads();

    // ---- build As[r=c_local][k=j] (pad k>=17 with 0)
    const float* ms = msrs;
    const float* rs = msrs + 128;
    #pragma unroll
    for (int it = 0; it < 16; ++it) {
        int idx = it * 256 + tid;
        int r = idx & 127, k = idx >> 7;
        float val = 0.f;
        if (k < Jn) {
            float xv = xb[(size_t)k * Cn + c0 + r];
            val = (xv - ms[r]) * rs[r] * g1s[k] + be1s[k];
        }
        *(u16*)((char*)As + r * 64 + ((((k >> 3) ^ (r & 3))) << 4) + ((k & 7) << 1)) = f2bf(val);
    }
    __syncthreads();

    int rb = wave * 32;                    // this wave's 32 c-rows
    f32x4 acc2[2][2];
    #pragma unroll
    for (int i = 0; i < 2; ++i)
        #pragma unroll
        for (int j = 0; j < 2; ++j) acc2[i][j] = (f32x4)0.f;

    // A-frags for GEMM1 (K=32: one step)
    bf8_t af1[2];
    #pragma unroll
    for (int rf = 0; rf < 2; ++rf) {
        int r = rb + rf * 16 + (lane & 15);
        af1[rf] = *(const bf8_t*)((const char*)As + r * 64 + ((((lane >> 4)) ^ (r & 3)) << 4));
    }

    #pragma unroll
    for (int ch = 0; ch < 2; ++ch) {
        // ---- GEMM1: hidden chunk ch (t_local 0..127)
        f32x4 acc1[2][8];
        #pragma unroll
        for (int rf = 0; rf < 2; ++rf)
            #pragma unroll
            for (int cf = 0; cf < 8; ++cf) acc1[rf][cf] = (f32x4)0.f;
        #pragma unroll
        for (int cf = 0; cf < 8; ++cf) {
            int t = ch * 128 + cf * 16 + (lane & 15);
            bf8_t bfw = *(const bf8_t*)((const char*)W11s + t * 64 + ((((lane >> 4)) ^ (t & 3)) << 4));
            #pragma unroll
            for (int rf = 0; rf < 2; ++rf)
                acc1[rf][cf] = __builtin_amdgcn_mfma_f32_16x16x32_bf16(af1[rf], bfw, acc1[rf][cf], 0, 0, 0);
        }
        // ---- bias + gelu -> Hs (own rows only)
        #pragma unroll
        for (int rf = 0; rf < 2; ++rf) {
            int cbase = rb + rf * 16 + ((lane >> 4) << 2);
            #pragma unroll
            for (int cf = 0; cf < 8; ++cf) {
                int tl = cf * 16 + (lane & 15);
                float bv = b11s[ch * 128 + tl];
                #pragma unroll
                for (int i = 0; i < 4; ++i) {
                    float h = gelu_exact(acc1[rf][cf][i] + bv);
                    int c = cbase + i;
                    *(u16*)((char*)Hs + c * 256 + ((((tl >> 3) ^ (c & 7))) << 4) + ((tl & 7) << 1)) = f2bf(h);
                }
            }
        }
        // ---- GEMM2: accumulate over this chunk's 128 k (4 steps of 32)
        #pragma unroll
        for (int kt = 0; kt < 4; ++kt) {
            bf8_t bh[2];
            #pragma unroll
            for (int cf = 0; cf < 2; ++cf) {
                int c = rb + cf * 16 + (lane & 15);
                int tc = kt * 4 + (lane >> 4);          // chunk-of-8 index within Hs row
                bh[cf] = *(const bf8_t*)((const char*)Hs + c * 256 + ((tc ^ (c & 7)) << 4));
            }
            #pragma unroll
            for (int jf = 0; jf < 2; ++jf) {
                int j = jf * 16 + (lane & 15);
                int tc = ch * 16 + kt * 4 + (lane >> 4); // global chunk index within W12s row
                bf8_t aw = *(const bf8_t*)((const char*)W12s + j * 512 + ((tc ^ (j & 7)) << 4));
                #pragma unroll
                for (int cf = 0; cf < 2; ++cf)
                    acc2[jf][cf] = __builtin_amdgcn_mfma_f32_16x16x32_bf16(aw, bh[cf], acc2[jf][cf], 0, 0, 0);
            }
        }
    }

    // ---- epilogue: out[b][j][c] = x + mlp + b12[j]
    #pragma unroll
    for (int jf = 0; jf < 2; ++jf) {
        #pragma unroll
        for (int cf = 0; cf < 2; ++cf) {
            int c = c0 + rb + cf * 16 + (lane & 15);
            #pragma unroll
            for (int i = 0; i < 4; ++i) {
                int j = jf * 16 + ((lane >> 4) << 2) + i;
                if (j < Jn) {
                    size_t off = (size_t)b * (Jn * Cn) + (size_t)j * Cn + c;
                    out[off] = x[off] + acc2[jf][cf][i] + b12[j];
                }
            }
        }
    }
}

// ---------------------------------------------------------------- LN2 over C per (b,j) row; writes xn2 bf16
__global__ __launch_bounds__(256) void ln2_kernel(const float* __restrict__ X2,
        const float* __restrict__ g2, const float* __restrict__ be2,
        u16* __restrict__ xn2)
{
    int row = blockIdx.x * 4 + (threadIdx.x >> 6);
    int lane = threadIdx.x & 63;
    const float* p = X2 + (size_t)row * Cn;
    float4 v0 = ((const float4*)p)[lane];
    float4 v1 = ((const float4*)p)[lane + 64];
    float s = v0.x + v0.y + v0.z + v0.w + v1.x + v1.y + v1.z + v1.w;
    float q = v0.x*v0.x + v0.y*v0.y + v0.z*v0.z + v0.w*v0.w
            + v1.x*v1.x + v1.y*v1.y + v1.z*v1.z + v1.w*v1.w;
    #pragma unroll
    for (int off = 32; off > 0; off >>= 1) { s += __shfl_xor(s, off); q += __shfl_xor(q, off); }
    float mean = s * (1.0f / Cn);
    float var = fmaxf(q * (1.0f / Cn) - mean * mean, 0.f);
    float rs = rsqrtf(var + EPSf);
    float4 ga = ((const float4*)g2)[lane],      ba = ((const float4*)be2)[lane];
    float4 gb = ((const float4*)g2)[lane + 64], bb = ((const float4*)be2)[lane + 64];
    uint2 w0, w1;
    w0.x = pk2((v0.x-mean)*rs*ga.x + ba.x, (v0.y-mean)*rs*ga.y + ba.y);
    w0.y = pk2((v0.z-mean)*rs*ga.z + ba.z, (v0.w-mean)*rs*ga.w + ba.w);
    w1.x = pk2((v1.x-mean)*rs*gb.x + bb.x, (v1.y-mean)*rs*gb.y + bb.y);
    w1.y = pk2((v1.z-mean)*rs*gb.z + bb.z, (v1.w-mean)*rs*gb.w + bb.w);
    ((uint2*)(xn2 + (size_t)row * Cn))[lane] = w0;
    ((uint2*)(xn2 + (size_t)row * Cn))[lane + 64] = w1;
}

// ---------------------------------------------------------------- MFMA GEMM: C(M x N) = A(M x K) * Bt(N x K)^T
// 128x128 tile, BK=32, 4 waves (2x2), 16x16x32 bf16 MFMA, dbuf LDS, chunk-XOR swizzle.
// EPI 0: outH = bf16(gelu(acc + bias[col]))    (ld Nld)
// EPI 1: outF += acc + (bias ? bias[col] : 0)  (ld Nld)
// EPI 2: outF += acc + bias[(row%17)*512+col]  (ld Nld)
template<int EPI>
__global__ __launch_bounds__(256) void gemm_bt(
    const u16* __restrict__ A, int ldA,
    const u16* __restrict__ Bt, int ldB,
    int K, int Nld,
    const float* __restrict__ bias,
    float* __restrict__ outF, u16* __restrict__ outH)
{
    __shared__ __align__(16) u16 As[2][128 * 32];
    __shared__ __align__(16) u16 Bs[2][128 * 32];
    int tid = threadIdx.x;
    int m0 = blockIdx.x * 128;
    int n0 = blockIdx.y * 128;
    int wave = tid >> 6, lane = tid & 63;
    int wr = wave >> 1, wc = wave & 1;

    const u16* aSrc[2]; const u16* bSrc[2];
    #pragma unroll
    for (int t = 0; t < 2; ++t) {
        int idx = t * 256 + tid;
        int r = idx >> 2;
        int cs = (idx & 3) ^ ((r >> 1) & 3);
        aSrc[t] = A  + (size_t)(m0 + r) * ldA + cs * 8;
        bSrc[t] = Bt + (size_t)(n0 + r) * ldB + cs * 8;
    }
    int aOff[4], bOff[4];
    #pragma unroll
    for (int i = 0; i < 4; ++i) {
        int ra = wr * 64 + i * 16 + (lane & 15);
        aOff[i] = ra * 64 + ((((lane >> 4)) ^ ((ra >> 1) & 3)) << 4);
        int rb = wc * 64 + i * 16 + (lane & 15);
        bOff[i] = rb * 64 + ((((lane >> 4)) ^ ((rb >> 1) & 3)) << 4);
    }

    f32x4 acc[4][4];
    #pragma unroll
    for (int i = 0; i < 4; ++i)
        #pragma unroll
        for (int j = 0; j < 4; ++j) acc[i][j] = (f32x4)0.f;

    int KT = K >> 5;
    #pragma unroll
    for (int t = 0; t < 2; ++t) {
        int idx = t * 256 + tid;
        gload_lds16(aSrc[t], (char*)&As[0][0] + idx * 16);
        gload_lds16(bSrc[t], (char*)&Bs[0][0] + idx * 16);
    }
    int cur = 0;
    for (int kt = 0; kt < KT; ++kt) {
        asm volatile("s_waitcnt vmcnt(0)" ::: "memory");
        __syncthreads();
        if (kt + 1 < KT) {
            int k0 = (kt + 1) << 5;
            #pragma unroll
            for (int t = 0; t < 2; ++t) {
                int idx = t * 256 + tid;
                gload_lds16(aSrc[t] + k0, (char*)&As[cur ^ 1][0] + idx * 16);
                gload_lds16(bSrc[t] + k0, (char*)&Bs[cur ^ 1][0] + idx * 16);
            }
        }
        bf8_t af[4], bfr[4];
        #pragma unroll
        for (int i = 0; i < 4; ++i) {
            af[i]  = *(const bf8_t*)((const char*)&As[cur][0] + aOff[i]);
            bfr[i] = *(const bf8_t*)((const char*)&Bs[cur][0] + bOff[i]);
        }
        #pragma unroll
        for (int mi = 0; mi < 4; ++mi)
            #pragma unroll
            for (int ni = 0; ni < 4; ++ni)
                acc[mi][ni] = __builtin_amdgcn_mfma_f32_16x16x32_bf16(af[mi], bfr[ni], acc[mi][ni], 0, 0, 0);
        cur ^= 1;
    }

    #pragma unroll
    for (int mi = 0; mi < 4; ++mi) {
        int rbase = m0 + wr * 64 + mi * 16 + ((lane >> 4) << 2);
        #pragma unroll
        for (int ni = 0; ni < 4; ++ni) {
            int col = n0 + wc * 64 + ni * 16 + (lane & 15);
            if (EPI == 0) {
                float bv = bias[col];
                #pragma unroll
                for (int i = 0; i < 4; ++i) {
                    float v = gelu_exact(acc[mi][ni][i] + bv);
                    outH[(size_t)(rbase + i) * Nld + col] = f2bf(v);
                }
            } else if (EPI == 1) {
                float bv = bias ? bias[col] : 0.f;
                #pragma unroll
                for (int i = 0; i < 4; ++i) {
                    size_t off = (size_t)(rbase + i) * Nld + col;
                    outF[off] += acc[mi][ni][i] + bv;
                }
            } else {
                #pragma unroll
                for (int i = 0; i < 4; ++i) {
                    int row = rbase + i;
                    int w = row % Jn;
                    size_t off = (size_t)row * Nld + col;
                    outF[off] += acc[mi][ni][i] + bias[w * Cn + col];
                }
            }
        }
    }
}

// ----------------------------------------------------------------
extern "C" void kernel_launch(void* const* d_in, const int* in_sizes, int n_in,
                              void* d_out, int out_size, void* d_ws, size_t ws_size,
                              hipStream_t stream)
{
    (void)in_sizes; (void)n_in; (void)out_size; (void)ws_size;
    const float* x   = (const float*)d_in[0];
    const float* adj = (const float*)d_in[1];
    const float* g1  = (const float*)d_in[2];
    const float* be1 = (const float*)d_in[3];
    const float* g2  = (const float*)d_in[4];
    const float* be2 = (const float*)d_in[5];
    const float* Wg1 = (const float*)d_in[6];
    const float* bg1 = (const float*)d_in[7];
    const float* Wg2 = (const float*)d_in[8];
    const float* bg2 = (const float*)d_in[9];
    const float* W11 = (const float*)d_in[10];
    const float* b11 = (const float*)d_in[11];
    const float* W12 = (const float*)d_in[12];
    const float* b12 = (const float*)d_in[13];
    const float* W21 = (const float*)d_in[14];
    const float* b21 = (const float*)d_in[15];
    const float* W22 = (const float*)d_in[16];
    const float* b22 = (const float*)d_in[17];
    float* out = (float*)d_out;

    // ws layout (bytes, all 16B-aligned)
    char* p = (char*)d_ws;
    float* mean1  = (float*)p;                 p += (size_t)Bn * Cn * 4;
    float* rstd1  = (float*)p;                 p += (size_t)Bn * Cn * 4;
    u16*   xn2    = (u16*)p;                   p += (size_t)Mrows * Cn * 2;
    u16*   W21b   = (u16*)p;                   p += (size_t)CHn * Cn * 2;
    u16*   W22b   = (u16*)p;                   p += (size_t)CHn * Cn * 2;
    u16*   Wg1t   = (u16*)p;                   p += (size_t)Cn * Kn * Cn * 2;
    u16*   Wg2t   = (u16*)p;                   p += (size_t)Cn * Kn * Cn * 2;
    float* bias2a = (float*)p;                 p += (size_t)Jn * Cn * 4;
    float* bias2b = (float*)p;                 p += (size_t)Jn * Cn * 4;
    u16*   W11p   = (u16*)p;                   p += (size_t)TOKn * 32 * 2;
    u16*   W12p   = (u16*)p;                   p += (size_t)32 * TOKn * 2;
    u16*   xmix   = (u16*)p;                   // max 69632*1536*2 = 213.9 MB (shared with H)
    u16*   Hbuf   = xmix;

    prep_kernel<<<2050, 256, 0, stream>>>(W21, W22, Wg1, Wg2, bg1, bg2, adj, W11, W12,
                                          W21b, W22b, Wg1t, Wg2t, bias2a, bias2b, W11p, W12p);
    // stage 1
    premix_kernel<1><<<Bn, 256, 0, stream>>>(x, (const u16*)nullptr, adj, g1, be1, mean1, rstd1, xmix);
    {
        dim3 g(Cn / 128, Bn);
        mlp1_mfma<<<g, 256, 0, stream>>>(x, mean1, rstd1, g1, be1, W11p, b11, W12p, b12, out);
    }
    {
        dim3 g(Mrows / 128, Cn / 128);
        gemm_bt<2><<<g, 256, 0, stream>>>(xmix, Kn * Cn, Wg1t, Kn * Cn, Kn * Cn, Cn, bias2a, out, (u16*)nullptr);
    }
    // stage 2
    ln2_kernel<<<Mrows / 4, 256, 0, stream>>>(out, g2, be2, xn2);
    for (int h = 0; h < 2; ++h) {
        int hc = h * 1024;
        dim3 ga(Mrows / 128, 1024 / 128);
        gemm_bt<0><<<ga, 256, 0, stream>>>(xn2, Cn, W21b + (size_t)hc * Cn, Cn, Cn, 1024, b21 + hc, (float*)nullptr, Hbuf);
        dim3 gb(Mrows / 128, Cn / 128);
        gemm_bt<1><<<gb, 256, 0, stream>>>(Hbuf, 1024, W22b + hc, CHn, 1024, Cn, (h == 0) ? b22 : (const float*)nullptr, out, (u16*)nullptr);
    }
    premix_kernel<2><<<Bn, 256, 0, stream>>>((const float*)nullptr, xn2, adj, (const float*)nullptr, (const float*)nullptr,
                                             (float*)nullptr, (float*)nullptr, xmix);
    {
        dim3 g(Mrows / 128, Cn / 128);
        gemm_bt<2><<<g, 256, 0, stream>>>(xmix, Kn * Cn, Wg2t, Kn * Cn, Kn * Cn, Cn, bias2b, out, (u16*)nullptr);
    }
}

// Round 4
// 1981.571 us; speedup vs baseline: 8.6952x; 1.2398x over previous
//
#include <hip/hip_runtime.h>
#include <hip/hip_bf16.h>

#define Bn   4096
#define Jn   17
#define Cn   512
#define Kn   3
#define TOKn 256
#define CHn  2048
#define EPSf 1e-5f
#define Mrows (Bn * Jn)          // 69632 GEMM rows

typedef unsigned short u16;
typedef short bf8_t __attribute__((ext_vector_type(8)));
typedef float f32x4 __attribute__((ext_vector_type(4)));

__device__ __forceinline__ float gelu_exact(float x) {
    return 0.5f * x * (1.0f + erff(x * 0.70710678118654752440f));
}
// tanh-form gelu via hw exp2+rcp: x*(1 - 1/(1+exp2(x*(2.3022652+0.1029474*x^2))))
// max abs err ~3e-4 vs exact; saturates correctly for |x| large.
__device__ __forceinline__ float gelu_fast(float x) {
    float x2 = x * x;
    float z = x * __builtin_fmaf(0.1029474f, x2, 2.3022652f);
    float e = __builtin_amdgcn_exp2f(z);
    float r = __builtin_amdgcn_rcpf(e + 1.0f);
    return x * (1.0f - r);
}
__device__ __forceinline__ float bf2f(u16 u) {
    union { float f; unsigned int i; } w; w.i = ((unsigned int)u) << 16; return w.f;
}
__device__ __forceinline__ u16 f2bf(float f) {
    union { float f; unsigned int i; } w; w.f = f;
    unsigned int x = w.i;
    return (u16)((x + 0x7fffu + ((x >> 16) & 1u)) >> 16);
}
__device__ __forceinline__ unsigned pk2(float a, float b) {
    return (unsigned)f2bf(a) | ((unsigned)f2bf(b) << 16);
}
__device__ __forceinline__ void unpack2(unsigned u, float& a, float& b) {
    union { float f; unsigned int i; } t;
    t.i = u << 16;          a = t.f;
    t.i = u & 0xffff0000u;  b = t.f;
}
__device__ __forceinline__ void gload_lds16(const void* g, void* l) {
    __builtin_amdgcn_global_load_lds(
        (const __attribute__((address_space(1))) void*)g,
        (__attribute__((address_space(3))) void*)l, 16, 0, 0);
}

// ---------------------------------------------------------------- prep: bf16 casts + Wg permute + bias2 tables + mlp1 padded weights
__global__ __launch_bounds__(256) void prep_kernel(
    const float* __restrict__ W21, const float* __restrict__ W22,
    const float* __restrict__ Wg1, const float* __restrict__ Wg2,
    const float* __restrict__ bg1, const float* __restrict__ bg2,
    const float* __restrict__ adj,
    const float* __restrict__ W11, const float* __restrict__ W12,
    u16* __restrict__ W21b, u16* __restrict__ W22b,
    u16* __restrict__ Wg1t, u16* __restrict__ Wg2t,
    float* __restrict__ bias2a, float* __restrict__ bias2b,
    u16* __restrict__ W11p, u16* __restrict__ W12p)
{
    int bid = blockIdx.x, tid = threadIdx.x;
    if (bid < 1024) {
        const float* src = (bid < 512) ? W21 : W22;
        u16* dst = (bid < 512) ? W21b : W22b;
        size_t base = (size_t)(bid & 511) * 2048 + (size_t)tid * 8;
        float4 v0 = *(const float4*)(src + base);
        float4 v1 = *(const float4*)(src + base + 4);
        uint4 o;
        o.x = pk2(v0.x, v0.y); o.y = pk2(v0.z, v0.w);
        o.z = pk2(v1.x, v1.y); o.w = pk2(v1.z, v1.w);
        *(uint4*)(dst + base) = o;
    } else if (bid < 2048) {
        const float* src = (bid < 1536) ? Wg1 : Wg2;
        u16* dst = (bid < 1536) ? Wg1t : Wg2t;
        int rbase = ((bid - 1024) & 511) * 3;
        int c = tid * 2;
        for (int rr = 0; rr < 3; ++rr) {
            int ro = rbase + rr;                  // over (k,o)
            int k = ro >> 9, o = ro & 511;
            const float* sp = src + ((size_t)k * Cn + o) * Cn + c;
            float2 v = *(const float2*)sp;
            *(unsigned*)(dst + (size_t)o * (Kn * Cn) + k * Cn + c) = pk2(v.x, v.y);
        }
    } else if (bid == 2048) {
        __shared__ float adjcs[Kn][Jn];
        for (int i = tid; i < Kn * Jn; i += 256) {
            int k = i / Jn, w = i - k * Jn;
            float s = 0.f;
            for (int v = 0; v < Jn; ++v) s += adj[k * (Jn * Jn) + v * Jn + w];
            adjcs[k][w] = s;
        }
        __syncthreads();
        for (int i = tid; i < Jn * Cn; i += 256) {
            int w = i >> 9, o = i & 511;
            float sa = 0.f, sb = 0.f;
            #pragma unroll
            for (int k = 0; k < Kn; ++k) {
                sa += bg1[k * Cn + o] * adjcs[k][w];
                sb += bg2[k * Cn + o] * adjcs[k][w];
            }
            bias2a[i] = sa; bias2b[i] = sb;
        }
    } else {
        // W11p [256][32] (pad j>=17 with 0), W12p [32][256] (pad j>=17 rows with 0)
        for (int idx = tid; idx < TOKn * 32; idx += 256) {
            int t = idx >> 5, k = idx & 31;
            W11p[idx] = (k < Jn) ? f2bf(W11[t * Jn + k]) : (u16)0;
        }
        for (int idx = tid; idx < 32 * TOKn; idx += 256) {
            int j = idx >> 8, t = idx & 255;
            W12p[idx] = (j < Jn) ? f2bf(W12[j * TOKn + t]) : (u16)0;
        }
    }
}

// ---------------------------------------------------------------- premix: (optional LN1) + adjacency mix -> xmix[(b,w)][k*512+c] bf16
template<int STAGE>
__global__ __launch_bounds__(256) void premix_kernel(
    const float* __restrict__ x,          // stage1
    const u16* __restrict__ xn2,          // stage2
    const float* __restrict__ adj,
    const float* __restrict__ g1, const float* __restrict__ be1,
    float* __restrict__ mean1, float* __restrict__ rstd1,
    u16* __restrict__ xmix)
{
    __shared__ float xsh[Jn][Cn];         // 34 KB
    __shared__ float coef[Kn][Jn][Jn];    // [k][w][v] (stage1: *g1[v])
    __shared__ float s0sh[Kn][Jn];        // sum_v adj*be1
    __shared__ float s1sh[Kn][Jn];        // sum_v coef
    __shared__ float msh[Cn], rsh[Cn];
    int b = blockIdx.x, tid = threadIdx.x;

    for (int i = tid; i < Kn * Jn * Jn; i += 256) {
        int k = i / (Jn * Jn); int rem = i - k * (Jn * Jn);
        int v = rem / Jn; int w = rem - v * Jn;
        float av = adj[i];
        coef[k][w][v] = (STAGE == 1) ? av * g1[v] : av;
    }
    if (STAGE == 1) {
        const float* xp = x + (size_t)b * (Jn * Cn);
        for (int i = tid; i < (Jn * Cn) / 4; i += 256)
            ((float4*)&xsh[0][0])[i] = ((const float4*)xp)[i];
    } else {
        const u16* xp = xn2 + (size_t)b * (Jn * Cn);
        for (int i = tid; i < (Jn * Cn) / 8; i += 256) {
            uint4 u = ((const uint4*)xp)[i];
            float* d = &(&xsh[0][0])[i * 8];
            unpack2(u.x, d[0], d[1]); unpack2(u.y, d[2], d[3]);
            unpack2(u.z, d[4], d[5]); unpack2(u.w, d[6], d[7]);
        }
    }
    __syncthreads();
    if (STAGE == 1) {
        for (int c = tid; c < Cn; c += 256) {
            float s = 0.f, q = 0.f;
            #pragma unroll
            for (int v = 0; v < Jn; ++v) { float t = xsh[v][c]; s += t; q += t * t; }
            float m = s * (1.0f / Jn);
            float var = fmaxf(q * (1.0f / Jn) - m * m, 0.f);
            float r = rsqrtf(var + EPSf);
            msh[c] = m; rsh[c] = r;
            mean1[(size_t)b * Cn + c] = m;
            rstd1[(size_t)b * Cn + c] = r;
        }
    }
    if (tid < Kn * Jn) {
        int k = tid / Jn, w = tid - k * Jn;
        float s0 = 0.f, s1 = 0.f;
        #pragma unroll
        for (int v = 0; v < Jn; ++v) {
            if (STAGE == 1) s0 += adj[k * (Jn * Jn) + v * Jn + w] * be1[v];
            s1 += coef[k][w][v];
        }
        s0sh[k][w] = s0; s1sh[k][w] = s1;
    }
    __syncthreads();
    u16* orow = xmix + (size_t)b * Jn * (Kn * Cn);
    for (int k = 0; k < Kn; ++k)
        for (int w = 0; w < Jn; ++w) {
            float cf[Jn];
            #pragma unroll
            for (int v = 0; v < Jn; ++v) cf[v] = coef[k][w][v];
            float ss1 = s1sh[k][w], ss0 = s0sh[k][w];
            for (int c = tid; c < Cn; c += 256) {
                float dot = 0.f;
                #pragma unroll
                for (int v = 0; v < Jn; ++v) dot += cf[v] * xsh[v][c];
                float val;
                if (STAGE == 1) val = rsh[c] * (dot - msh[c] * ss1) + ss0;
                else            val = dot;
                orow[(size_t)w * (Kn * Cn) + k * Cn + c] = f2bf(val);
            }
        }
}

// ---------------------------------------------------------------- MLP1 (token mix) via MFMA
// block = (b, 128-chunk of c). GEMM1 (swapped): D1[t][c] = W11p * xn^T, K=32 (one step);
// lane holds 4 contiguous t per c -> b64 packed H store. GEMM2: out = x + W12p@H^T + b12, K=256.
// Hidden in 2 chunks of 128; each wave owns 32 c-cols end-to-end (no inter-wave barriers after As).
__global__ __launch_bounds__(256) void mlp1_mfma(
    const float* __restrict__ x,
    const float* __restrict__ mean1, const float* __restrict__ rstd1,
    const float* __restrict__ g1, const float* __restrict__ be1,
    const u16* __restrict__ W11p,   // [256][32] bf16 padded
    const float* __restrict__ b11,
    const u16* __restrict__ W12p,   // [32][256] bf16 padded
    const float* __restrict__ b12,
    float* __restrict__ out)
{
    __shared__ __align__(16) u16 As[128 * 32];     // xn tile [c][j], chunk-swizzled
    __shared__ __align__(16) u16 Hs[128 * 128];    // hidden chunk [c][t], chunk-swizzled
    __shared__ __align__(16) u16 W11s[TOKn * 32];  // swizzled
    __shared__ __align__(16) u16 W12s[32 * TOKn];  // swizzled
    __shared__ __align__(16) float b11s[TOKn];
    __shared__ __align__(16) float msrs[256];      // [0:128)=mean, [128:256)=rstd
    __shared__ float g1s[32], be1s[32];

    int tid = threadIdx.x;
    int lane = tid & 63, wave = tid >> 6;
    int b = blockIdx.y, c0 = blockIdx.x * 128;
    const float* xb = x + (size_t)b * (Jn * Cn);

    // ---- stage (all dests wave-linear for global_load_lds)
    #pragma unroll
    for (int t = 0; t < 4; ++t) {          // W11s: 1024 x 16B, src chunk s^(row&3)
        int idx = t * 256 + tid;
        int tt = idx >> 2, s = idx & 3;
        gload_lds16(W11p + tt * 32 + ((s ^ (tt & 3)) << 3), (char*)W11s + idx * 16);
    }
    #pragma unroll
    for (int t = 0; t < 4; ++t) {          // W12s: 1024 x 16B, src chunk s^(row&7)
        int idx = t * 256 + tid;
        int j = idx >> 5, s = idx & 31;
        gload_lds16(W12p + j * TOKn + ((s ^ (j & 7)) << 3), (char*)W12s + idx * 16);
    }
    if (wave == 0) gload_lds16(b11 + lane * 4, (char*)b11s + lane * 16);
    if (wave == 1) {
        const float* src = (lane < 32) ? (mean1 + (size_t)b * Cn + c0 + lane * 4)
                                       : (rstd1 + (size_t)b * Cn + c0 + (lane - 32) * 4);
        gload_lds16(src, (char*)msrs + lane * 16);
    }
    if (tid < Jn) { g1s[tid] = g1[tid]; be1s[tid] = be1[tid]; }
    asm volatile("s_waitcnt vmcnt(0)" ::: "memory");
    __syncthreads();

    // ---- build As[r=c_local][k=j] packed u32 (2 j per thread; pad k>=17 with 0)
    const float* ms = msrs;
    const float* rs = msrs + 128;
    #pragma unroll
    for (int it = 0; it < 8; ++it) {
        int idx = it * 256 + tid;            // 2048: r x 16 j-pairs
        int r = idx & 127, k = (idx >> 7) << 1;
        float mr = ms[r], rr = rs[r];
        float v0 = 0.f, v1 = 0.f;
        if (k < Jn)     v0 = (xb[(size_t)k * Cn + c0 + r] - mr) * rr * g1s[k] + be1s[k];
        if (k + 1 < Jn) v1 = (xb[(size_t)(k + 1) * Cn + c0 + r] - mr) * rr * g1s[k + 1] + be1s[k + 1];
        *(unsigned*)((char*)As + r * 64 + ((((k >> 3) ^ (r & 3))) << 4) + ((k & 7) << 1)) = pk2(v0, v1);
    }
    __syncthreads();

    int rb = wave * 32;                    // this wave's 32 c-columns
    f32x4 acc2[2][2];
    #pragma unroll
    for (int i = 0; i < 2; ++i)
        #pragma unroll
        for (int j = 0; j < 2; ++j) acc2[i][j] = (f32x4)0.f;

    // B-frags (xn, cols c) for GEMM1 — reused across both hidden chunks
    bf8_t bfc[2];
    #pragma unroll
    for (int cf = 0; cf < 2; ++cf) {
        int c = rb + cf * 16 + (lane & 15);
        bfc[cf] = *(const bf8_t*)((const char*)As + c * 64 + ((((lane >> 4)) ^ (c & 3)) << 4));
    }

    #pragma unroll
    for (int ch = 0; ch < 2; ++ch) {
        // ---- GEMM1 (swapped): D1[t][c], t over this chunk's 128
        f32x4 acc1[8][2];
        #pragma unroll
        for (int tf = 0; tf < 8; ++tf)
            #pragma unroll
            for (int cf = 0; cf < 2; ++cf) acc1[tf][cf] = (f32x4)0.f;
        #pragma unroll
        for (int tf = 0; tf < 8; ++tf) {
            int t = ch * 128 + tf * 16 + (lane & 15);
            bf8_t aw = *(const bf8_t*)((const char*)W11s + t * 64 + ((((lane >> 4)) ^ (t & 3)) << 4));
            #pragma unroll
            for (int cf = 0; cf < 2; ++cf)
                acc1[tf][cf] = __builtin_amdgcn_mfma_f32_16x16x32_bf16(aw, bfc[cf], acc1[tf][cf], 0, 0, 0);
        }
        // ---- bias + gelu -> Hs (4 contiguous t per lane -> one b64 write per frag)
        #pragma unroll
        for (int tf = 0; tf < 8; ++tf) {
            int t0 = tf * 16 + ((lane >> 4) << 2);           // local t of elem 0
            float b0 = b11s[ch * 128 + t0 + 0];
            float b1 = b11s[ch * 128 + t0 + 1];
            float b2 = b11s[ch * 128 + t0 + 2];
            float b3 = b11s[ch * 128 + t0 + 3];
            #pragma unroll
            for (int cf = 0; cf < 2; ++cf) {
                int c = rb + cf * 16 + (lane & 15);
                float h0 = gelu_fast(acc1[tf][cf][0] + b0);
                float h1 = gelu_fast(acc1[tf][cf][1] + b1);
                float h2 = gelu_fast(acc1[tf][cf][2] + b2);
                float h3 = gelu_fast(acc1[tf][cf][3] + b3);
                uint2 w; w.x = pk2(h0, h1); w.y = pk2(h2, h3);
                *(uint2*)((char*)Hs + c * 256 + ((((t0 >> 3) ^ (c & 7))) << 4) + ((t0 & 7) << 1)) = w;
            }
        }
        // ---- GEMM2: accumulate over this chunk's 128 k (4 steps of 32)
        #pragma unroll
        for (int kt = 0; kt < 4; ++kt) {
            bf8_t bh[2];
            #pragma unroll
            for (int cf = 0; cf < 2; ++cf) {
                int c = rb + cf * 16 + (lane & 15);
                int tc = kt * 4 + (lane >> 4);          // chunk-of-8 index within Hs row
                bh[cf] = *(const bf8_t*)((const char*)Hs + c * 256 + ((tc ^ (c & 7)) << 4));
            }
            #pragma unroll
            for (int jf = 0; jf < 2; ++jf) {
                int j = jf * 16 + (lane & 15);
                int tc = ch * 16 + kt * 4 + (lane >> 4); // global chunk index within W12s row
                bf8_t aw = *(const bf8_t*)((const char*)W12s + j * 512 + ((tc ^ (j & 7)) << 4));
                #pragma unroll
                for (int cf = 0; cf < 2; ++cf)
                    acc2[jf][cf] = __builtin_amdgcn_mfma_f32_16x16x32_bf16(aw, bh[cf], acc2[jf][cf], 0, 0, 0);
            }
        }
    }

    // ---- epilogue: out[b][j][c] = x + mlp + b12[j]
    #pragma unroll
    for (int jf = 0; jf < 2; ++jf) {
        #pragma unroll
        for (int cf = 0; cf < 2; ++cf) {
            int c = c0 + rb + cf * 16 + (lane & 15);
            #pragma unroll
            for (int i = 0; i < 4; ++i) {
                int j = jf * 16 + ((lane >> 4) << 2) + i;
                if (j < Jn) {
                    size_t off = (size_t)b * (Jn * Cn) + (size_t)j * Cn + c;
                    out[off] = x[off] + acc2[jf][cf][i] + b12[j];
                }
            }
        }
    }
}

// ---------------------------------------------------------------- LN2 over C per (b,j) row; writes xn2 bf16
__global__ __launch_bounds__(256) void ln2_kernel(const float* __restrict__ X2,
        const float* __restrict__ g2, const float* __restrict__ be2,
        u16* __restrict__ xn2)
{
    int row = blockIdx.x * 4 + (threadIdx.x >> 6);
    int lane = threadIdx.x & 63;
    const float* p = X2 + (size_t)row * Cn;
    float4 v0 = ((const float4*)p)[lane];
    float4 v1 = ((const float4*)p)[lane + 64];
    float s = v0.x + v0.y + v0.z + v0.w + v1.x + v1.y + v1.z + v1.w;
    float q = v0.x*v0.x + v0.y*v0.y + v0.z*v0.z + v0.w*v0.w
            + v1.x*v1.x + v1.y*v1.y + v1.z*v1.z + v1.w*v1.w;
    #pragma unroll
    for (int off = 32; off > 0; off >>= 1) { s += __shfl_xor(s, off); q += __shfl_xor(q, off); }
    float mean = s * (1.0f / Cn);
    float var = fmaxf(q * (1.0f / Cn) - mean * mean, 0.f);
    float rs = rsqrtf(var + EPSf);
    float4 ga = ((const float4*)g2)[lane],      ba = ((const float4*)be2)[lane];
    float4 gb = ((const float4*)g2)[lane + 64], bb = ((const float4*)be2)[lane + 64];
    uint2 w0, w1;
    w0.x = pk2((v0.x-mean)*rs*ga.x + ba.x, (v0.y-mean)*rs*ga.y + ba.y);
    w0.y = pk2((v0.z-mean)*rs*ga.z + ba.z, (v0.w-mean)*rs*ga.w + ba.w);
    w1.x = pk2((v1.x-mean)*rs*gb.x + bb.x, (v1.y-mean)*rs*gb.y + bb.y);
    w1.y = pk2((v1.z-mean)*rs*gb.z + bb.z, (v1.w-mean)*rs*gb.w + bb.w);
    ((uint2*)(xn2 + (size_t)row * Cn))[lane] = w0;
    ((uint2*)(xn2 + (size_t)row * Cn))[lane + 64] = w1;
}

// ---------------------------------------------------------------- MFMA GEMM: C(M x N) = A(M x K) * Bt(N x K)^T
// 128x128 tile, BK=32, 4 waves (2x2), 16x16x32 bf16 MFMA, dbuf LDS, chunk-XOR swizzle.
// EPI 0: outH = bf16(gelu(acc + bias[col]))    (ld Nld)
// EPI 1: outF += acc + (bias ? bias[col] : 0)  (ld Nld)
// EPI 2: outF += acc + bias[(row%17)*512+col]  (ld Nld)
template<int EPI>
__global__ __launch_bounds__(256) void gemm_bt(
    const u16* __restrict__ A, int ldA,
    const u16* __restrict__ Bt, int ldB,
    int K, int Nld,
    const float* __restrict__ bias,
    float* __restrict__ outF, u16* __restrict__ outH)
{
    __shared__ __align__(16) u16 As[2][128 * 32];
    __shared__ __align__(16) u16 Bs[2][128 * 32];
    int tid = threadIdx.x;
    int m0 = blockIdx.x * 128;
    int n0 = blockIdx.y * 128;
    int wave = tid >> 6, lane = tid & 63;
    int wr = wave >> 1, wc = wave & 1;

    const u16* aSrc[2]; const u16* bSrc[2];
    #pragma unroll
    for (int t = 0; t < 2; ++t) {
        int idx = t * 256 + tid;
        int r = idx >> 2;
        int cs = (idx & 3) ^ ((r >> 1) & 3);
        aSrc[t] = A  + (size_t)(m0 + r) * ldA + cs * 8;
        bSrc[t] = Bt + (size_t)(n0 + r) * ldB + cs * 8;
    }
    int aOff[4], bOff[4];
    #pragma unroll
    for (int i = 0; i < 4; ++i) {
        int ra = wr * 64 + i * 16 + (lane & 15);
        aOff[i] = ra * 64 + ((((lane >> 4)) ^ ((ra >> 1) & 3)) << 4);
        int rb = wc * 64 + i * 16 + (lane & 15);
        bOff[i] = rb * 64 + ((((lane >> 4)) ^ ((rb >> 1) & 3)) << 4);
    }

    f32x4 acc[4][4];
    #pragma unroll
    for (int i = 0; i < 4; ++i)
        #pragma unroll
        for (int j = 0; j < 4; ++j) acc[i][j] = (f32x4)0.f;

    int KT = K >> 5;
    #pragma unroll
    for (int t = 0; t < 2; ++t) {
        int idx = t * 256 + tid;
        gload_lds16(aSrc[t], (char*)&As[0][0] + idx * 16);
        gload_lds16(bSrc[t], (char*)&Bs[0][0] + idx * 16);
    }
    int cur = 0;
    for (int kt = 0; kt < KT; ++kt) {
        asm volatile("s_waitcnt vmcnt(0)" ::: "memory");
        __syncthreads();
        if (kt + 1 < KT) {
            int k0 = (kt + 1) << 5;
            #pragma unroll
            for (int t = 0; t < 2; ++t) {
                int idx = t * 256 + tid;
                gload_lds16(aSrc[t] + k0, (char*)&As[cur ^ 1][0] + idx * 16);
                gload_lds16(bSrc[t] + k0, (char*)&Bs[cur ^ 1][0] + idx * 16);
            }
        }
        bf8_t af[4], bfr[4];
        #pragma unroll
        for (int i = 0; i < 4; ++i) {
            af[i]  = *(const bf8_t*)((const char*)&As[cur][0] + aOff[i]);
            bfr[i] = *(const bf8_t*)((const char*)&Bs[cur][0] + bOff[i]);
        }
        #pragma unroll
        for (int mi = 0; mi < 4; ++mi)
            #pragma unroll
            for (int ni = 0; ni < 4; ++ni)
                acc[mi][ni] = __builtin_amdgcn_mfma_f32_16x16x32_bf16(af[mi], bfr[ni], acc[mi][ni], 0, 0, 0);
        cur ^= 1;
    }

    #pragma unroll
    for (int mi = 0; mi < 4; ++mi) {
        int rbase = m0 + wr * 64 + mi * 16 + ((lane >> 4) << 2);
        #pragma unroll
        for (int ni = 0; ni < 4; ++ni) {
            int col = n0 + wc * 64 + ni * 16 + (lane & 15);
            if (EPI == 0) {
                float bv = bias[col];
                #pragma unroll
                for (int i = 0; i < 4; ++i) {
                    float v = gelu_fast(acc[mi][ni][i] + bv);
                    outH[(size_t)(rbase + i) * Nld + col] = f2bf(v);
                }
            } else if (EPI == 1) {
                float bv = bias ? bias[col] : 0.f;
                #pragma unroll
                for (int i = 0; i < 4; ++i) {
                    size_t off = (size_t)(rbase + i) * Nld + col;
                    outF[off] += acc[mi][ni][i] + bv;
                }
            } else {
                #pragma unroll
                for (int i = 0; i < 4; ++i) {
                    int row = rbase + i;
                    int w = row % Jn;
                    size_t off = (size_t)row * Nld + col;
                    outF[off] += acc[mi][ni][i] + bias[w * Cn + col];
                }
            }
        }
    }
}

// ----------------------------------------------------------------
extern "C" void kernel_launch(void* const* d_in, const int* in_sizes, int n_in,
                              void* d_out, int out_size, void* d_ws, size_t ws_size,
                              hipStream_t stream)
{
    (void)in_sizes; (void)n_in; (void)out_size; (void)ws_size;
    const float* x   = (const float*)d_in[0];
    const float* adj = (const float*)d_in[1];
    const float* g1  = (const float*)d_in[2];
    const float* be1 = (const float*)d_in[3];
    const float* g2  = (const float*)d_in[4];
    const float* be2 = (const float*)d_in[5];
    const float* Wg1 = (const float*)d_in[6];
    const float* bg1 = (const float*)d_in[7];
    const float* Wg2 = (const float*)d_in[8];
    const float* bg2 = (const float*)d_in[9];
    const float* W11 = (const float*)d_in[10];
    const float* b11 = (const float*)d_in[11];
    const float* W12 = (const float*)d_in[12];
    const float* b12 = (const float*)d_in[13];
    const float* W21 = (const float*)d_in[14];
    const float* b21 = (const float*)d_in[15];
    const float* W22 = (const float*)d_in[16];
    const float* b22 = (const float*)d_in[17];
    float* out = (float*)d_out;

    // ws layout (bytes, all 16B-aligned)
    char* p = (char*)d_ws;
    float* mean1  = (float*)p;                 p += (size_t)Bn * Cn * 4;
    float* rstd1  = (float*)p;                 p += (size_t)Bn * Cn * 4;
    u16*   xn2    = (u16*)p;                   p += (size_t)Mrows * Cn * 2;
    u16*   W21b   = (u16*)p;                   p += (size_t)CHn * Cn * 2;
    u16*   W22b   = (u16*)p;                   p += (size_t)CHn * Cn * 2;
    u16*   Wg1t   = (u16*)p;                   p += (size_t)Cn * Kn * Cn * 2;
    u16*   Wg2t   = (u16*)p;                   p += (size_t)Cn * Kn * Cn * 2;
    float* bias2a = (float*)p;                 p += (size_t)Jn * Cn * 4;
    float* bias2b = (float*)p;                 p += (size_t)Jn * Cn * 4;
    u16*   W11p   = (u16*)p;                   p += (size_t)TOKn * 32 * 2;
    u16*   W12p   = (u16*)p;                   p += (size_t)32 * TOKn * 2;
    u16*   xmix   = (u16*)p;                   // max 69632*1536*2 = 213.9 MB (shared with H)
    u16*   Hbuf   = xmix;

    prep_kernel<<<2050, 256, 0, stream>>>(W21, W22, Wg1, Wg2, bg1, bg2, adj, W11, W12,
                                          W21b, W22b, Wg1t, Wg2t, bias2a, bias2b, W11p, W12p);
    // stage 1
    premix_kernel<1><<<Bn, 256, 0, stream>>>(x, (const u16*)nullptr, adj, g1, be1, mean1, rstd1, xmix);
    {
        dim3 g(Cn / 128, Bn);
        mlp1_mfma<<<g, 256, 0, stream>>>(x, mean1, rstd1, g1, be1, W11p, b11, W12p, b12, out);
    }
    {
        dim3 g(Mrows / 128, Cn / 128);
        gemm_bt<2><<<g, 256, 0, stream>>>(xmix, Kn * Cn, Wg1t, Kn * Cn, Kn * Cn, Cn, bias2a, out, (u16*)nullptr);
    }
    // stage 2
    ln2_kernel<<<Mrows / 4, 256, 0, stream>>>(out, g2, be2, xn2);
    for (int h = 0; h < 2; ++h) {
        int hc = h * 1024;
        dim3 ga(Mrows / 128, 1024 / 128);
        gemm_bt<0><<<ga, 256, 0, stream>>>(xn2, Cn, W21b + (size_t)hc * Cn, Cn, Cn, 1024, b21 + hc, (float*)nullptr, Hbuf);
        dim3 gb(Mrows / 128, Cn / 128);
        gemm_bt<1><<<gb, 256, 0, stream>>>(Hbuf, 1024, W22b + hc, CHn, 1024, Cn, (h == 0) ? b22 : (const float*)nullptr, out, (u16*)nullptr);
    }
    premix_kernel<2><<<Bn, 256, 0, stream>>>((const float*)nullptr, xn2, adj, (const float*)nullptr, (const float*)nullptr,
                                             (float*)nullptr, (float*)nullptr, xmix);
    {
        dim3 g(Mrows / 128, Cn / 128);
        gemm_bt<2><<<g, 256, 0, stream>>>(xmix, Kn * Cn, Wg2t, Kn * Cn, Kn * Cn, Cn, bias2b, out, (u16*)nullptr);
    }
}